// Round 4
// baseline (1170.932 us; speedup 1.0000x reference)
//
#include <hip/hip_runtime.h>
#include <hip/hip_bf16.h>
#include <cstddef>

// Problem constants (fixed by reference)
#define N_USERS   100000
#define N_ITEMS   100000
#define N_NODES   200000
#define D         64
#define BATCH     2048
#define HIST      50
#define N_ITEMS_PAD 100096   // padded to multiple of 128 (block item-chunk)

#define BUCKET_SHIFT 9                       // 512 rows per bucket
#define N_BUCKETS ((N_NODES + 511) >> 9)     // 391
#define CHUNK 8192                           // edges per binning block (32/thread stash)
#define EPT   (CHUNK / 256)                  // 32 edges per thread
// Fixed bucket capacity: counts ~ Binomial(12.8M, 512/200K): mean 32768, sigma 181.
// 36864 = mean + 22 sigma. Deterministic seed-0 dataset; guarded per-edge anyway.
#define BCAP 36864
#define PSLICES 4                            // k_binP blocks per bucket
#define SLICE_LEN (BCAP / PSLICES)           // 9216

// k_scores geometry: batch-stationary waves, item-streaming.
#define ISPLITS 92                           // 100096/32 = 3128 tiles = 92 * 34
#define TPS (N_ITEMS_PAD / 32 / ISPLITS)     // 34 item-tiles per x-block

typedef __attribute__((ext_vector_type(8))) short short8;
typedef __attribute__((ext_vector_type(16))) float float16;
typedef __attribute__((ext_vector_type(2)))  float floatx2;

__device__ __forceinline__ ushort f2bf(float x) {  // fp32 -> bf16 RNE
    unsigned u = __float_as_uint(x);
    return (ushort)((u + 0x7FFF + ((u >> 16) & 1)) >> 16);
}
__device__ __forceinline__ unsigned char f2fp8(float x) {  // fp32 -> fp8 e4m3 (OCP), RNE+sat
    int p = __builtin_amdgcn_cvt_pk_fp8_f32(x, x, 0, false);
    return (unsigned char)(p & 0xFF);
}
__device__ __forceinline__ float fp82f(unsigned char u) {  // fp8 e4m3 -> fp32
    return __builtin_amdgcn_cvt_f32_fp8((int)u, 0);
}

// ---------------- pass A: bin edges into fixed-capacity bucket arenas ----------------
// ONE return-LDS-atomic per edge (claim), stash (p<<18|row) in regs, reserve the
// bucket run after the barrier, then place (adj_col reloaded, L2-warm). Also counts
// per-row degree via no-return global atomics (L2-distributed over 800 KB) so
// pass B never needs a counting phase.
__global__ __launch_bounds__(256) void k_binA(const int* __restrict__ adj_row,
                                              const int* __restrict__ adj_col,
                                              int* __restrict__ deg,
                                              int* __restrict__ gcursor, int* __restrict__ staged,
                                              int nedges) {
    __shared__ int cur[N_BUCKETS];
    __shared__ int lbase[N_BUCKETS];
    int t = threadIdx.x;
    int base = blockIdx.x * CHUNK;
    for (int i = t; i < N_BUCKETS; i += 256) cur[i] = 0;
    __syncthreads();
    int stash[EPT];
#pragma unroll
    for (int k = 0; k < EPT; ++k) {
        int e = base + k * 256 + t;
        if (e < nedges) {
            int r = adj_row[e];
            atomicAdd(&deg[r], 1);                    // no-return global, L2-resident
            int b = r >> BUCKET_SHIFT;
            int p = atomicAdd(&cur[b], 1);            // claim slot (<= 8191, 13 bits)
            stash[k] = (p << 18) | r;                 // r: 18 bits
        } else stash[k] = -1;
    }
    __syncthreads();
    for (int b = t; b < N_BUCKETS; b += 256) {
        int c = cur[b];
        int s = (c > 0) ? atomicAdd(&gcursor[b], c) : 0;
        lbase[b] = b * BCAP + s;
    }
    __syncthreads();
#pragma unroll
    for (int k = 0; k < EPT; ++k) {
        int v = stash[k];
        if (v >= 0) {
            int e = base + k * 256 + t;
            int c = adj_col[e];
            int r = v & 0x3FFFF;
            int b = r >> BUCKET_SHIFT;
            int pos = lbase[b] + (v >> 18);
            if (pos < (b + 1) * BCAP)                 // overflow guard (never fires)
                staged[pos] = ((r & 511) << 18) | c;
        }
    }
}

// ---------------- pass S: per-bucket scan of deg -> rowptr, seed row cursors; fused init ----------------
__global__ __launch_bounds__(512) void k_binS(const int* __restrict__ deg,
                                              int* __restrict__ rowptr, int* __restrict__ gcur2,
                                              const float* __restrict__ user_emb,
                                              const float* __restrict__ item_emb,
                                              unsigned char* __restrict__ w0) {
    __shared__ int cnt[512];
    __shared__ int scn[512];
    int b = blockIdx.x, t = threadIdx.x;
    int r = (b << BUCKET_SHIFT) + t;
    int myc = (r < N_NODES) ? deg[r] : 0;
    cnt[t] = myc;
    scn[t] = myc;
    __syncthreads();
    for (int off = 1; off < 512; off <<= 1) {
        int v = (t >= off) ? scn[t - off] : 0;
        __syncthreads();
        scn[t] += v;
        __syncthreads();
    }
    int gpos = b * BCAP + (scn[t] - myc);
    if (r < N_NODES) { rowptr[r] = gpos; gcur2[r] = gpos; }
    // fused init: w0 = fp8(64 * x0 / sqrt(max(deg,1))) for this bucket's 512 rows
    int r0 = b << BUCKET_SHIFT;
    for (int f = t; f < 512 * 16; f += 512) {
        int lr = f >> 4;
        int row = r0 + lr;
        if (row >= N_NODES) continue;
        const float4* src = (row < N_USERS)
            ? ((const float4*)user_emb) + (size_t)row * 16 + (f & 15)
            : ((const float4*)item_emb) + (size_t)(row - (N_USERS - 1)) * 16 + (f & 15);
        float4 v = *src;
        int dg = cnt[lr]; if (dg < 1) dg = 1;
        float sc = 64.f * __frsqrt_rn((float)dg);
        uchar4 o;
        o.x = f2fp8(v.x * sc); o.y = f2fp8(v.y * sc);
        o.z = f2fp8(v.z * sc); o.w = f2fp8(v.w * sc);
        ((uchar4*)w0)[(size_t)row * 16 + (f & 15)] = o;
    }
}

// ---------------- pass P: place staged edges into row-packed ecols via global row cursors ----------------
// 4 slice-blocks per bucket; writes confined to the bucket's 147 KB ecols window
// (L2-resident -> no write amplification); cursors L2-hot (64 atomics/row).
__global__ __launch_bounds__(256) void k_binP(const int* __restrict__ gcursor,
                                              const int* __restrict__ staged,
                                              int* __restrict__ gcur2, int* __restrict__ ecols) {
    int b = blockIdx.x, t = threadIdx.x;
    int nb = gcursor[b]; if (nb > BCAP) nb = BCAP;
    int off = blockIdx.y * SLICE_LEN;
    int end = off + SLICE_LEN; if (end > nb) end = nb;
    size_t es = (size_t)b * BCAP;
    int rbase = b << BUCKET_SHIFT;
    for (int e = off + t; e < end; e += 256) {
        int v = staged[es + e];
        int row = rbase + (v >> 18);
        int p = atomicAdd(&gcur2[row], 1);
        ecols[p] = (v & 0x3FFFF) << 6;   // byte offset into fp8 node rows
    }
}

// ---------------- propagate (fp8 z-space): w_out[r] = (1/deg_r) * sum w_in[c] ----------------
#define ACC8(v)                                               \
    a01 += __builtin_amdgcn_cvt_pk_f32_fp8((int)(v).x, false); \
    a23 += __builtin_amdgcn_cvt_pk_f32_fp8((int)(v).x, true);  \
    a45 += __builtin_amdgcn_cvt_pk_f32_fp8((int)(v).y, false); \
    a67 += __builtin_amdgcn_cvt_pk_f32_fp8((int)(v).y, true);

__global__ __launch_bounds__(256) void k_prop(const int* __restrict__ rowptr, const int* __restrict__ deg,
                                              const int* __restrict__ ecols,
                                              const unsigned char* __restrict__ x_in,
                                              unsigned char* __restrict__ x_out) {
    int w = blockIdx.x * 4 + (threadIdx.x >> 6);
    int lane = threadIdx.x & 63;
    int slot = lane >> 3;          // one of 8 edge slots
    int d8 = (lane & 7) * 8;       // 8 dims per lane
    int s = rowptr[w];
    int cnt = deg[w];
    const int* ec = ecols + s;
    floatx2 a01 = {0.f, 0.f}, a23 = {0.f, 0.f}, a45 = {0.f, 0.f}, a67 = {0.f, 0.f};
    int p = 0;
    for (; p + 64 <= cnt; p += 64) {
        int c0 = ec[p + slot];
        int c1 = ec[p + 8 + slot];
        int c2 = ec[p + 16 + slot];
        int c3 = ec[p + 24 + slot];
        int c4 = ec[p + 32 + slot];
        int c5 = ec[p + 40 + slot];
        int c6 = ec[p + 48 + slot];
        int c7 = ec[p + 56 + slot];
        uint2 v0 = *(const uint2*)(x_in + c0 + d8);
        uint2 v1 = *(const uint2*)(x_in + c1 + d8);
        uint2 v2 = *(const uint2*)(x_in + c2 + d8);
        uint2 v3 = *(const uint2*)(x_in + c3 + d8);
        uint2 v4 = *(const uint2*)(x_in + c4 + d8);
        uint2 v5 = *(const uint2*)(x_in + c5 + d8);
        uint2 v6 = *(const uint2*)(x_in + c6 + d8);
        uint2 v7 = *(const uint2*)(x_in + c7 + d8);
        ACC8(v0) ACC8(v1) ACC8(v2) ACC8(v3)
        ACC8(v4) ACC8(v5) ACC8(v6) ACC8(v7)
    }
    for (; p + 32 <= cnt; p += 32) {
        int c0 = ec[p + slot];
        int c1 = ec[p + 8 + slot];
        int c2 = ec[p + 16 + slot];
        int c3 = ec[p + 24 + slot];
        uint2 v0 = *(const uint2*)(x_in + c0 + d8);
        uint2 v1 = *(const uint2*)(x_in + c1 + d8);
        uint2 v2 = *(const uint2*)(x_in + c2 + d8);
        uint2 v3 = *(const uint2*)(x_in + c3 + d8);
        ACC8(v0) ACC8(v1) ACC8(v2) ACC8(v3)
    }
    for (; p < cnt; p += 8) {
        int rem = cnt - p;                     // >= 1
        int sl = (slot < rem) ? slot : 0;
        int c = ec[p + sl];
        uint2 v = *(const uint2*)(x_in + c + d8);
        if (slot < rem) { ACC8(v) }
    }
    // cross-slot reduce: lanes L, L+8, ..., L+56 hold same dims, different edges
#pragma unroll
    for (int off = 32; off >= 8; off >>= 1) {
        a01.x += __shfl_down(a01.x, off); a01.y += __shfl_down(a01.y, off);
        a23.x += __shfl_down(a23.x, off); a23.y += __shfl_down(a23.y, off);
        a45.x += __shfl_down(a45.x, off); a45.y += __shfl_down(a45.y, off);
        a67.x += __shfl_down(a67.x, off); a67.y += __shfl_down(a67.y, off);
    }
    if (lane < 8) {
        float inv = (cnt > 0) ? 1.f / (float)cnt : 0.f;
        int w01 = __builtin_amdgcn_cvt_pk_fp8_f32(a01.x * inv, a01.y * inv, 0, false);
        w01     = __builtin_amdgcn_cvt_pk_fp8_f32(a23.x * inv, a23.y * inv, w01, true);
        int w23 = __builtin_amdgcn_cvt_pk_fp8_f32(a45.x * inv, a45.y * inv, 0, false);
        w23     = __builtin_amdgcn_cvt_pk_fp8_f32(a67.x * inv, a67.y * inv, w23, true);
        uint2 o; o.x = (unsigned)w01; o.y = (unsigned)w23;
        *(uint2*)(x_out + (size_t)w * D + d8) = o;
    }
}

// ---------------- item latents: bf16( 0.25*item_emb + sqrt(deg)/256*(w1+w2+w3) ), zero-pad ----------------
__global__ void k_conv_items(const float* __restrict__ item_emb, const int* __restrict__ deg,
                             const unsigned char* __restrict__ w1, const unsigned char* __restrict__ w2,
                             const unsigned char* __restrict__ w3, ushort* __restrict__ item_bf) {
    int f = blockIdx.x * 256 + threadIdx.x;    // one 4-dim group
    if (f >= N_ITEMS_PAD * (D / 4)) return;
    int row = f >> 4, c4 = f & 15;
    ushort4 o;
    if (row < N_ITEMS) {
        int node = N_USERS + row;
        int dg = deg[node]; if (dg < 1) dg = 1;
        float s = sqrtf((float)dg) * (1.f / 256.f);    // sqrt(deg)/(64 scale * 4 avg)
        float4 e4 = ((const float4*)(item_emb + (size_t)(row + 1) * D))[c4];
        size_t n4 = (size_t)node * 16 + c4;
        uchar4 a = ((const uchar4*)w1)[n4];
        uchar4 b = ((const uchar4*)w2)[n4];
        uchar4 c = ((const uchar4*)w3)[n4];
        o.x = f2bf(0.25f * e4.x + s * (fp82f(a.x) + fp82f(b.x) + fp82f(c.x)));
        o.y = f2bf(0.25f * e4.y + s * (fp82f(a.y) + fp82f(b.y) + fp82f(c.y)));
        o.z = f2bf(0.25f * e4.z + s * (fp82f(a.z) + fp82f(b.z) + fp82f(c.z)));
        o.w = f2bf(0.25f * e4.w + s * (fp82f(a.w) + fp82f(b.w) + fp82f(c.w)));
    } else {
        o.x = o.y = o.z = o.w = 0;   // pad rows -> score 0 -> exp = 1 (subtract 96 in k_loss)
    }
    ((ushort4*)item_bf)[f] = o;
}

// ---------------- pred (bf16 copy) + label score ----------------
__global__ __launch_bounds__(256) void k_pred(const int* __restrict__ user_seqs, const int* __restrict__ his,
                                              const int* __restrict__ next_items,
                                              const float* __restrict__ user_emb, const float* __restrict__ item_emb,
                                              const int* __restrict__ deg,
                                              const unsigned char* __restrict__ w1, const unsigned char* __restrict__ w2,
                                              const unsigned char* __restrict__ w3,
                                              ushort* __restrict__ pred_bf, float* __restrict__ slabel) {
    int b = blockIdx.x * 4 + (threadIdx.x >> 6);
    int lane = threadIdx.x & 63;
    int u = user_seqs[b];
    float hsum = 0.f; int cnt = 0;
    for (int j = 0; j < HIST; ++j) {
        int it = his[b * HIST + j];
        cnt += (it != 0);
        hsum += item_emb[(size_t)it * D + lane];   // item_emb[0] is all-zero (pad)
    }
    int du = deg[u]; if (du < 1) du = 1;
    float su = sqrtf((float)du) * (1.f / 256.f);
    size_t ur = (size_t)u * D + lane;
    float ulat = 0.25f * user_emb[ur] + su * (fp82f(w1[ur]) + fp82f(w2[ur]) + fp82f(w3[ur]));
    float pv = ulat + hsum / (float)cnt;
    pred_bf[(size_t)b * D + lane] = f2bf(pv);
    int lab = next_items[b] - 1;
    int node = N_USERS + lab;
    int di = deg[node]; if (di < 1) di = 1;
    float si = sqrtf((float)di) * (1.f / 256.f);
    size_t nr = (size_t)node * D + lane;
    float ilat = 0.25f * item_emb[(size_t)(lab + 1) * D + lane]
               + si * (fp82f(w1[nr]) + fp82f(w2[nr]) + fp82f(w3[nr]));
    float tv = pv * ilat;
#pragma unroll
    for (int off = 32; off > 0; off >>= 1) tv += __shfl_down(tv, off);
    if (lane == 0) slabel[b] = tv;
}

// ---------------- MFMA scores + max-free sumexp (batch-stationary) ----------------
__global__ __launch_bounds__(256) void k_scores(const ushort* __restrict__ item_bf,
                                                const ushort* __restrict__ pred_bf,
                                                float* __restrict__ sumexp) {
    int t = threadIdx.x, wv = t >> 6, lane = t & 63;
    int l31 = lane & 31;
    int khalf = (lane >> 5) * 8;   // which 8-elem k-half this lane holds

    int brow = blockIdx.y * 128 + wv * 32 + l31;        // this lane's batch column
    const ushort* pb = pred_bf + (size_t)brow * D + khalf;
    short8 b0 = *(const short8*)(pb);
    short8 b1 = *(const short8*)(pb + 16);
    short8 b2 = *(const short8*)(pb + 32);
    short8 b3 = *(const short8*)(pb + 48);

    const ushort* ib = item_bf + ((size_t)blockIdx.x * (TPS * 32) + l31) * D + khalf;
    float acc = 0.f;
    for (int tt = 0; tt < TPS; tt += 2) {
        const ushort* i0 = ib + (size_t)tt * (32 * D);
        const ushort* i1 = i0 + (32 * D);
        short8 a00 = *(const short8*)(i0);
        short8 a01 = *(const short8*)(i0 + 16);
        short8 a02 = *(const short8*)(i0 + 32);
        short8 a03 = *(const short8*)(i0 + 48);
        short8 a10 = *(const short8*)(i1);
        short8 a11 = *(const short8*)(i1 + 16);
        short8 a12 = *(const short8*)(i1 + 32);
        short8 a13 = *(const short8*)(i1 + 48);
        float16 c0 = {0.f};
        float16 c1 = {0.f};
        c0 = __builtin_amdgcn_mfma_f32_32x32x16_bf16(a00, b0, c0, 0, 0, 0);
        c1 = __builtin_amdgcn_mfma_f32_32x32x16_bf16(a10, b0, c1, 0, 0, 0);
        c0 = __builtin_amdgcn_mfma_f32_32x32x16_bf16(a01, b1, c0, 0, 0, 0);
        c1 = __builtin_amdgcn_mfma_f32_32x32x16_bf16(a11, b1, c1, 0, 0, 0);
        c0 = __builtin_amdgcn_mfma_f32_32x32x16_bf16(a02, b2, c0, 0, 0, 0);
        c1 = __builtin_amdgcn_mfma_f32_32x32x16_bf16(a12, b2, c1, 0, 0, 0);
        c0 = __builtin_amdgcn_mfma_f32_32x32x16_bf16(a03, b3, c0, 0, 0, 0);
        c1 = __builtin_amdgcn_mfma_f32_32x32x16_bf16(a13, b3, c1, 0, 0, 0);
        float s0 = 0.f, s1 = 0.f, s2 = 0.f, s3 = 0.f;
#pragma unroll
        for (int r = 0; r < 16; r += 4) {
            s0 += __expf(c0[r]);
            s1 += __expf(c0[r + 1]);
            s2 += __expf(c0[r + 2]);
            s3 += __expf(c0[r + 3]);
        }
#pragma unroll
        for (int r = 0; r < 16; r += 4) {
            s0 += __expf(c1[r]);
            s1 += __expf(c1[r + 1]);
            s2 += __expf(c1[r + 2]);
            s3 += __expf(c1[r + 3]);
        }
        acc += (s0 + s1) + (s2 + s3);
    }
    // lane L and L+32 hold the two item-row halves of the same batch col
    acc += __shfl_down(acc, 32);
    if (lane < 32) unsafeAtomicAdd(&sumexp[brow], acc);
}

// ---------------- final loss reduce ----------------
__global__ __launch_bounds__(256) void k_loss(const float* __restrict__ sumexp, const float* __restrict__ slabel,
                                              float* __restrict__ out) {
    __shared__ float ws[4];
    int t = threadIdx.x;
    float v = 0.f;
    for (int i = t; i < BATCH; i += 256)
        v += __logf(sumexp[i] - 96.0f) - slabel[i];   // -96: padded items contribute exp(0)=1 each
#pragma unroll
    for (int off = 32; off > 0; off >>= 1) v += __shfl_down(v, off);
    if ((t & 63) == 0) ws[t >> 6] = v;
    __syncthreads();
    if (t == 0) out[0] = (ws[0] + ws[1] + ws[2] + ws[3]) * (1.f / (float)BATCH);
}

extern "C" void kernel_launch(void* const* d_in, const int* in_sizes, int n_in,
                              void* d_out, int out_size, void* d_ws, size_t ws_size,
                              hipStream_t stream) {
    const int*   user_seqs = (const int*)d_in[0];
    const int*   his       = (const int*)d_in[1];
    const int*   next_itm  = (const int*)d_in[2];
    const int*   adj_row   = (const int*)d_in[3];
    const int*   adj_col   = (const int*)d_in[4];
    const float* user_emb  = (const float*)d_in[6];
    const float* item_emb  = (const float*)d_in[7];
    float* out = (float*)d_out;
    int nedges = in_sizes[3];   // 12,800,000

    // Workspace layout (~185 MB)
    unsigned char* w0 = (unsigned char*)d_ws;              // 12.8 MB each
    unsigned char* w1 = w0 + (size_t)N_NODES * D;
    unsigned char* w2 = w1 + (size_t)N_NODES * D;
    unsigned char* w3 = w2 + (size_t)N_NODES * D;
    float*  slabel = (float*)(w3 + (size_t)N_NODES * D);   // 2,048
    float*  sumexp = slabel + BATCH;                       // 2,048   (zeroed)
    int*    gcursor= (int*)(sumexp + BATCH);               // 391     (zeroed)
    int*    deg    = gcursor + N_BUCKETS;                  // 200,000 (zeroed)
    int*    rowptr = deg + N_NODES;                        // 200,000
    int*    gcur2  = rowptr + N_NODES;                     // 200,000
    int*    staged = gcur2 + N_NODES;                      // 391*36864 ints (57.7 MB)
    int*    ecols  = staged + (size_t)N_BUCKETS * BCAP;    // 391*36864 ints (57.7 MB)
    ushort* item_bf = (ushort*)(ecols + (size_t)N_BUCKETS * BCAP);  // 100096*64 ushort
    ushort* pred_bf = item_bf + (size_t)N_ITEMS_PAD * D;   // 131072 ushort

    // zero sumexp + gcursor + deg in one shot (contiguous)
    hipError_t _e = hipMemsetAsync(sumexp, 0, (size_t)(BATCH + N_BUCKETS + N_NODES) * sizeof(int), stream);
    (void)_e;

    int nchunks = (nedges + CHUNK - 1) / CHUNK;
    k_binA<<<nchunks, 256, 0, stream>>>(adj_row, adj_col, deg, gcursor, staged, nedges);
    k_binS<<<N_BUCKETS, 512, 0, stream>>>(deg, rowptr, gcur2, user_emb, item_emb, w0);
    dim3 pgrid(N_BUCKETS, PSLICES);
    k_binP<<<pgrid, 256, 0, stream>>>(gcursor, staged, gcur2, ecols);

    k_prop<<<N_NODES / 4, 256, 0, stream>>>(rowptr, deg, ecols, w0, w1);
    k_prop<<<N_NODES / 4, 256, 0, stream>>>(rowptr, deg, ecols, w1, w2);
    k_prop<<<N_NODES / 4, 256, 0, stream>>>(rowptr, deg, ecols, w2, w3);

    k_conv_items<<<(N_ITEMS_PAD * (D / 4) + 255) / 256, 256, 0, stream>>>(item_emb, deg, w1, w2, w3, item_bf);
    k_pred<<<BATCH / 4, 256, 0, stream>>>(user_seqs, his, next_itm, user_emb, item_emb, deg,
                                          w1, w2, w3, pred_bf, slabel);

    dim3 gs(ISPLITS, BATCH / 128);
    k_scores<<<gs, 256, 0, stream>>>(item_bf, pred_bf, sumexp);

    k_loss<<<1, 256, 0, stream>>>(sumexp, slabel, out);
}

// Round 5
// 691.024 us; speedup vs baseline: 1.6945x; 1.6945x over previous
//
#include <hip/hip_runtime.h>
#include <hip/hip_bf16.h>
#include <cstddef>

// Problem constants (fixed by reference)
#define N_USERS   100000
#define N_ITEMS   100000
#define N_NODES   200000
#define D         64
#define BATCH     2048
#define HIST      50
#define N_ITEMS_PAD 100096   // padded to multiple of 128 (block item-chunk)

#define BUCKET_SHIFT 9                       // 512 rows per bucket
#define N_BUCKETS ((N_NODES + 511) >> 9)     // 391
#define CHUNK 8192                           // edges per binning block
#define EPT   (CHUNK / 256)                  // 32 edges per thread (8 x int4)
// Fixed bucket capacity: counts ~ Binomial(12.8M, 512/200K): mean 32768, sigma 181.
// 36864 = mean + 22 sigma. Deterministic seed-0 dataset; guarded per-edge anyway.
#define BCAP 36864

// k_scores geometry: batch-stationary waves, item-streaming.
#define ISPLITS 92                           // 100096/32 = 3128 tiles = 92 * 34
#define TPS (N_ITEMS_PAD / 32 / ISPLITS)     // 34 item-tiles per x-block

typedef __attribute__((ext_vector_type(8))) short short8;
typedef __attribute__((ext_vector_type(16))) float float16;
typedef __attribute__((ext_vector_type(2)))  float floatx2;

__device__ __forceinline__ ushort f2bf(float x) {  // fp32 -> bf16 RNE
    unsigned u = __float_as_uint(x);
    return (ushort)((u + 0x7FFF + ((u >> 16) & 1)) >> 16);
}
__device__ __forceinline__ unsigned char f2fp8(float x) {  // fp32 -> fp8 e4m3 (OCP), RNE+sat
    int p = __builtin_amdgcn_cvt_pk_fp8_f32(x, x, 0, false);
    return (unsigned char)(p & 0xFF);
}
__device__ __forceinline__ float fp82f(unsigned char u) {  // fp8 e4m3 -> fp32
    return __builtin_amdgcn_cvt_f32_fp8((int)u, 0);
}

// ---------------- pass A: bin edges into fixed-capacity bucket arenas ----------------
// ONE return-LDS-atomic per edge: claim slot in LDS cursor, stash (slot<<18)|row in
// registers, reserve the block's bucket runs after a barrier, then place records
// (adj_col int4-reloaded, L2-warm). NO global atomics anywhere (R2/R4 lesson:
// per-edge device-scope atomics bypass per-XCD L2 -> 300+ MB memory-side traffic).
__global__ __launch_bounds__(256) void k_binA(const int* __restrict__ adj_row,
                                              const int* __restrict__ adj_col,
                                              int* __restrict__ gcursor, int* __restrict__ staged,
                                              int nedges) {
    __shared__ int cur[N_BUCKETS];
    __shared__ int lbase[N_BUCKETS];
    int t = threadIdx.x;
    int base = blockIdx.x * CHUNK;
    for (int i = t; i < N_BUCKETS; i += 256) cur[i] = 0;
    __syncthreads();
    int stash[EPT];
#pragma unroll
    for (int k = 0; k < EPT / 4; ++k) {
        int e0 = base + (k * 256 + t) * 4;
        if (e0 + 3 < nedges) {
            int4 r4 = *(const int4*)(adj_row + e0);
            int p;
            p = atomicAdd(&cur[r4.x >> BUCKET_SHIFT], 1); stash[4 * k    ] = (p << 18) | r4.x;
            p = atomicAdd(&cur[r4.y >> BUCKET_SHIFT], 1); stash[4 * k + 1] = (p << 18) | r4.y;
            p = atomicAdd(&cur[r4.z >> BUCKET_SHIFT], 1); stash[4 * k + 2] = (p << 18) | r4.z;
            p = atomicAdd(&cur[r4.w >> BUCKET_SHIFT], 1); stash[4 * k + 3] = (p << 18) | r4.w;
        } else {
#pragma unroll
            for (int j = 0; j < 4; ++j) {
                int e = e0 + j;
                if (e < nedges) {
                    int r = adj_row[e];
                    int p = atomicAdd(&cur[r >> BUCKET_SHIFT], 1);
                    stash[4 * k + j] = (p << 18) | r;
                } else stash[4 * k + j] = -1;
            }
        }
    }
    __syncthreads();
    for (int b = t; b < N_BUCKETS; b += 256) {
        int c = cur[b];
        int s = (c > 0) ? atomicAdd(&gcursor[b], c) : 0;
        lbase[b] = b * BCAP + s;
    }
    __syncthreads();
#pragma unroll
    for (int k = 0; k < EPT / 4; ++k) {
        int e0 = base + (k * 256 + t) * 4;
        if (e0 + 3 < nedges) {
            int4 c4 = *(const int4*)(adj_col + e0);
#pragma unroll
            for (int j = 0; j < 4; ++j) {
                int v = stash[4 * k + j];
                int c = (j == 0) ? c4.x : (j == 1) ? c4.y : (j == 2) ? c4.z : c4.w;
                int r = v & 0x3FFFF;
                int b = r >> BUCKET_SHIFT;
                int pos = lbase[b] + (v >> 18);
                if (pos < (b + 1) * BCAP)             // overflow guard (never fires)
                    staged[pos] = ((r & 511) << 18) | c;
            }
        } else {
#pragma unroll
            for (int j = 0; j < 4; ++j) {
                int v = stash[4 * k + j];
                if (v >= 0) {
                    int e = e0 + j;
                    int c = adj_col[e];
                    int r = v & 0x3FFFF;
                    int b = r >> BUCKET_SHIFT;
                    int pos = lbase[b] + (v >> 18);
                    if (pos < (b + 1) * BCAP)
                        staged[pos] = ((r & 511) << 18) | c;
                }
            }
        }
    }
}

// ---------------- pass B: per bucket, LDS count+scan -> packed ecols/rowptr/deg; fused init ----------------
// 512 threads: thread t owns row t of the bucket. Also computes
// w0 = fp8(64 * x0 / sqrt(max(deg,1))) for the bucket's 512 rows (init fused).
__global__ __launch_bounds__(512) void k_binB(const int* __restrict__ gcursor, const int* __restrict__ staged,
                                              int* __restrict__ ecols, int* __restrict__ rowptr,
                                              int* __restrict__ deg,
                                              const float* __restrict__ user_emb,
                                              const float* __restrict__ item_emb,
                                              unsigned char* __restrict__ w0) {
    __shared__ int cnt[512];
    __shared__ int scn[512];
    __shared__ int cur[512];
    int b = blockIdx.x, t = threadIdx.x;
    cnt[t] = 0;
    __syncthreads();
    int nb = gcursor[b]; if (nb > BCAP) nb = BCAP;
    size_t es = (size_t)b * BCAP;
    for (int e = t; e < nb; e += 512) atomicAdd(&cnt[staged[es + e] >> 18], 1);
    __syncthreads();
    int myc = cnt[t];
    scn[t] = myc;
    __syncthreads();
    for (int off = 1; off < 512; off <<= 1) {
        int v = (t >= off) ? scn[t - off] : 0;
        __syncthreads();
        scn[t] += v;
        __syncthreads();
    }
    int excl = scn[t] - myc;
    int r = (b << BUCKET_SHIFT) + t;
    int gpos = b * BCAP + excl;
    if (r < N_NODES) { rowptr[r] = gpos; deg[r] = myc; }
    cur[t] = gpos;
    __syncthreads();
    for (int e = t; e < nb; e += 512) {
        int v = staged[es + e];
        int pos = atomicAdd(&cur[v >> 18], 1);
        ecols[pos] = (v & 0x3FFFF) << 6;   // byte offset into fp8 node rows
    }
    // fused init for this bucket's rows (cnt[] is stable; cur/scn unused here)
    int r0 = b << BUCKET_SHIFT;
    for (int f = t; f < 512 * 16; f += 512) {
        int lr = f >> 4;
        int row = r0 + lr;
        if (row >= N_NODES) continue;
        const float4* src = (row < N_USERS)
            ? ((const float4*)user_emb) + (size_t)row * 16 + (f & 15)
            : ((const float4*)item_emb) + (size_t)(row - (N_USERS - 1)) * 16 + (f & 15);
        float4 v = *src;
        int dg = cnt[lr]; if (dg < 1) dg = 1;
        float sc = 64.f * __frsqrt_rn((float)dg);
        uchar4 o;
        o.x = f2fp8(v.x * sc); o.y = f2fp8(v.y * sc);
        o.z = f2fp8(v.z * sc); o.w = f2fp8(v.w * sc);
        ((uchar4*)w0)[(size_t)row * 16 + (f & 15)] = o;
    }
}

// ---------------- propagate (fp8 z-space): w_out[r] = (1/deg_r) * sum w_in[c] ----------------
// 8 lanes/edge x dwordx2 gathers; packed cvt + v_pk_add_f32 accumulators.
#define ACC8(v)                                               \
    a01 += __builtin_amdgcn_cvt_pk_f32_fp8((int)(v).x, false); \
    a23 += __builtin_amdgcn_cvt_pk_f32_fp8((int)(v).x, true);  \
    a45 += __builtin_amdgcn_cvt_pk_f32_fp8((int)(v).y, false); \
    a67 += __builtin_amdgcn_cvt_pk_f32_fp8((int)(v).y, true);

__global__ __launch_bounds__(256) void k_prop(const int* __restrict__ rowptr, const int* __restrict__ deg,
                                              const int* __restrict__ ecols,
                                              const unsigned char* __restrict__ x_in,
                                              unsigned char* __restrict__ x_out) {
    int w = blockIdx.x * 4 + (threadIdx.x >> 6);
    int lane = threadIdx.x & 63;
    int slot = lane >> 3;          // one of 8 edge slots
    int d8 = (lane & 7) * 8;       // 8 dims per lane
    int s = rowptr[w];
    int cnt = deg[w];
    const int* ec = ecols + s;
    floatx2 a01 = {0.f, 0.f}, a23 = {0.f, 0.f}, a45 = {0.f, 0.f}, a67 = {0.f, 0.f};
    int p = 0;
    for (; p + 64 <= cnt; p += 64) {
        int c0 = ec[p + slot];
        int c1 = ec[p + 8 + slot];
        int c2 = ec[p + 16 + slot];
        int c3 = ec[p + 24 + slot];
        int c4 = ec[p + 32 + slot];
        int c5 = ec[p + 40 + slot];
        int c6 = ec[p + 48 + slot];
        int c7 = ec[p + 56 + slot];
        uint2 v0 = *(const uint2*)(x_in + c0 + d8);
        uint2 v1 = *(const uint2*)(x_in + c1 + d8);
        uint2 v2 = *(const uint2*)(x_in + c2 + d8);
        uint2 v3 = *(const uint2*)(x_in + c3 + d8);
        uint2 v4 = *(const uint2*)(x_in + c4 + d8);
        uint2 v5 = *(const uint2*)(x_in + c5 + d8);
        uint2 v6 = *(const uint2*)(x_in + c6 + d8);
        uint2 v7 = *(const uint2*)(x_in + c7 + d8);
        ACC8(v0) ACC8(v1) ACC8(v2) ACC8(v3)
        ACC8(v4) ACC8(v5) ACC8(v6) ACC8(v7)
    }
    for (; p + 32 <= cnt; p += 32) {
        int c0 = ec[p + slot];
        int c1 = ec[p + 8 + slot];
        int c2 = ec[p + 16 + slot];
        int c3 = ec[p + 24 + slot];
        uint2 v0 = *(const uint2*)(x_in + c0 + d8);
        uint2 v1 = *(const uint2*)(x_in + c1 + d8);
        uint2 v2 = *(const uint2*)(x_in + c2 + d8);
        uint2 v3 = *(const uint2*)(x_in + c3 + d8);
        ACC8(v0) ACC8(v1) ACC8(v2) ACC8(v3)
    }
    for (; p < cnt; p += 8) {
        int rem = cnt - p;                     // >= 1
        int sl = (slot < rem) ? slot : 0;
        int c = ec[p + sl];
        uint2 v = *(const uint2*)(x_in + c + d8);
        if (slot < rem) { ACC8(v) }
    }
    // cross-slot reduce: lanes L, L+8, ..., L+56 hold same dims, different edges
#pragma unroll
    for (int off = 32; off >= 8; off >>= 1) {
        a01.x += __shfl_down(a01.x, off); a01.y += __shfl_down(a01.y, off);
        a23.x += __shfl_down(a23.x, off); a23.y += __shfl_down(a23.y, off);
        a45.x += __shfl_down(a45.x, off); a45.y += __shfl_down(a45.y, off);
        a67.x += __shfl_down(a67.x, off); a67.y += __shfl_down(a67.y, off);
    }
    if (lane < 8) {
        float inv = (cnt > 0) ? 1.f / (float)cnt : 0.f;
        int w01 = __builtin_amdgcn_cvt_pk_fp8_f32(a01.x * inv, a01.y * inv, 0, false);
        w01     = __builtin_amdgcn_cvt_pk_fp8_f32(a23.x * inv, a23.y * inv, w01, true);
        int w23 = __builtin_amdgcn_cvt_pk_fp8_f32(a45.x * inv, a45.y * inv, 0, false);
        w23     = __builtin_amdgcn_cvt_pk_fp8_f32(a67.x * inv, a67.y * inv, w23, true);
        uint2 o; o.x = (unsigned)w01; o.y = (unsigned)w23;
        *(uint2*)(x_out + (size_t)w * D + d8) = o;
    }
}

// ---------------- item latents: bf16( 0.25*item_emb + sqrt(deg)/256*(w1+w2+w3) ), zero-pad ----------------
__global__ void k_conv_items(const float* __restrict__ item_emb, const int* __restrict__ deg,
                             const unsigned char* __restrict__ w1, const unsigned char* __restrict__ w2,
                             const unsigned char* __restrict__ w3, ushort* __restrict__ item_bf) {
    int f = blockIdx.x * 256 + threadIdx.x;    // one 4-dim group
    if (f >= N_ITEMS_PAD * (D / 4)) return;
    int row = f >> 4, c4 = f & 15;
    ushort4 o;
    if (row < N_ITEMS) {
        int node = N_USERS + row;
        int dg = deg[node]; if (dg < 1) dg = 1;
        float s = sqrtf((float)dg) * (1.f / 256.f);    // sqrt(deg)/(64 scale * 4 avg)
        float4 e4 = ((const float4*)(item_emb + (size_t)(row + 1) * D))[c4];
        size_t n4 = (size_t)node * 16 + c4;
        uchar4 a = ((const uchar4*)w1)[n4];
        uchar4 b = ((const uchar4*)w2)[n4];
        uchar4 c = ((const uchar4*)w3)[n4];
        o.x = f2bf(0.25f * e4.x + s * (fp82f(a.x) + fp82f(b.x) + fp82f(c.x)));
        o.y = f2bf(0.25f * e4.y + s * (fp82f(a.y) + fp82f(b.y) + fp82f(c.y)));
        o.z = f2bf(0.25f * e4.z + s * (fp82f(a.z) + fp82f(b.z) + fp82f(c.z)));
        o.w = f2bf(0.25f * e4.w + s * (fp82f(a.w) + fp82f(b.w) + fp82f(c.w)));
    } else {
        o.x = o.y = o.z = o.w = 0;   // pad rows -> score 0 -> exp = 1 (subtract 96 in k_loss)
    }
    ((ushort4*)item_bf)[f] = o;
}

// ---------------- pred (bf16 copy) + label score ----------------
__global__ __launch_bounds__(256) void k_pred(const int* __restrict__ user_seqs, const int* __restrict__ his,
                                              const int* __restrict__ next_items,
                                              const float* __restrict__ user_emb, const float* __restrict__ item_emb,
                                              const int* __restrict__ deg,
                                              const unsigned char* __restrict__ w1, const unsigned char* __restrict__ w2,
                                              const unsigned char* __restrict__ w3,
                                              ushort* __restrict__ pred_bf, float* __restrict__ slabel) {
    int b = blockIdx.x * 4 + (threadIdx.x >> 6);
    int lane = threadIdx.x & 63;
    int u = user_seqs[b];
    float hsum = 0.f; int cnt = 0;
    for (int j = 0; j < HIST; ++j) {
        int it = his[b * HIST + j];
        cnt += (it != 0);
        hsum += item_emb[(size_t)it * D + lane];   // item_emb[0] is all-zero (pad)
    }
    int du = deg[u]; if (du < 1) du = 1;
    float su = sqrtf((float)du) * (1.f / 256.f);
    size_t ur = (size_t)u * D + lane;
    float ulat = 0.25f * user_emb[ur] + su * (fp82f(w1[ur]) + fp82f(w2[ur]) + fp82f(w3[ur]));
    float pv = ulat + hsum / (float)cnt;
    pred_bf[(size_t)b * D + lane] = f2bf(pv);
    int lab = next_items[b] - 1;
    int node = N_USERS + lab;
    int di = deg[node]; if (di < 1) di = 1;
    float si = sqrtf((float)di) * (1.f / 256.f);
    size_t nr = (size_t)node * D + lane;
    float ilat = 0.25f * item_emb[(size_t)(lab + 1) * D + lane]
               + si * (fp82f(w1[nr]) + fp82f(w2[nr]) + fp82f(w3[nr]));
    float tv = pv * ilat;
#pragma unroll
    for (int off = 32; off > 0; off >>= 1) tv += __shfl_down(tv, off);
    if (lane == 0) slabel[b] = tv;
}

// ---------------- MFMA scores + max-free sumexp (batch-stationary) ----------------
__global__ __launch_bounds__(256) void k_scores(const ushort* __restrict__ item_bf,
                                                const ushort* __restrict__ pred_bf,
                                                float* __restrict__ sumexp) {
    int t = threadIdx.x, wv = t >> 6, lane = t & 63;
    int l31 = lane & 31;
    int khalf = (lane >> 5) * 8;   // which 8-elem k-half this lane holds

    int brow = blockIdx.y * 128 + wv * 32 + l31;        // this lane's batch column
    const ushort* pb = pred_bf + (size_t)brow * D + khalf;
    short8 b0 = *(const short8*)(pb);
    short8 b1 = *(const short8*)(pb + 16);
    short8 b2 = *(const short8*)(pb + 32);
    short8 b3 = *(const short8*)(pb + 48);

    const ushort* ib = item_bf + ((size_t)blockIdx.x * (TPS * 32) + l31) * D + khalf;
    float acc = 0.f;
    for (int tt = 0; tt < TPS; tt += 2) {
        const ushort* i0 = ib + (size_t)tt * (32 * D);
        const ushort* i1 = i0 + (32 * D);
        short8 a00 = *(const short8*)(i0);
        short8 a01 = *(const short8*)(i0 + 16);
        short8 a02 = *(const short8*)(i0 + 32);
        short8 a03 = *(const short8*)(i0 + 48);
        short8 a10 = *(const short8*)(i1);
        short8 a11 = *(const short8*)(i1 + 16);
        short8 a12 = *(const short8*)(i1 + 32);
        short8 a13 = *(const short8*)(i1 + 48);
        float16 c0 = {0.f};
        float16 c1 = {0.f};
        c0 = __builtin_amdgcn_mfma_f32_32x32x16_bf16(a00, b0, c0, 0, 0, 0);
        c1 = __builtin_amdgcn_mfma_f32_32x32x16_bf16(a10, b0, c1, 0, 0, 0);
        c0 = __builtin_amdgcn_mfma_f32_32x32x16_bf16(a01, b1, c0, 0, 0, 0);
        c1 = __builtin_amdgcn_mfma_f32_32x32x16_bf16(a11, b1, c1, 0, 0, 0);
        c0 = __builtin_amdgcn_mfma_f32_32x32x16_bf16(a02, b2, c0, 0, 0, 0);
        c1 = __builtin_amdgcn_mfma_f32_32x32x16_bf16(a12, b2, c1, 0, 0, 0);
        c0 = __builtin_amdgcn_mfma_f32_32x32x16_bf16(a03, b3, c0, 0, 0, 0);
        c1 = __builtin_amdgcn_mfma_f32_32x32x16_bf16(a13, b3, c1, 0, 0, 0);
        float s0 = 0.f, s1 = 0.f, s2 = 0.f, s3 = 0.f;
#pragma unroll
        for (int r = 0; r < 16; r += 4) {
            s0 += __expf(c0[r]);
            s1 += __expf(c0[r + 1]);
            s2 += __expf(c0[r + 2]);
            s3 += __expf(c0[r + 3]);
        }
#pragma unroll
        for (int r = 0; r < 16; r += 4) {
            s0 += __expf(c1[r]);
            s1 += __expf(c1[r + 1]);
            s2 += __expf(c1[r + 2]);
            s3 += __expf(c1[r + 3]);
        }
        acc += (s0 + s1) + (s2 + s3);
    }
    // lane L and L+32 hold the two item-row halves of the same batch col
    acc += __shfl_down(acc, 32);
    if (lane < 32) unsafeAtomicAdd(&sumexp[brow], acc);
}

// ---------------- final loss reduce ----------------
__global__ __launch_bounds__(256) void k_loss(const float* __restrict__ sumexp, const float* __restrict__ slabel,
                                              float* __restrict__ out) {
    __shared__ float ws[4];
    int t = threadIdx.x;
    float v = 0.f;
    for (int i = t; i < BATCH; i += 256)
        v += __logf(sumexp[i] - 96.0f) - slabel[i];   // -96: padded items contribute exp(0)=1 each
#pragma unroll
    for (int off = 32; off > 0; off >>= 1) v += __shfl_down(v, off);
    if ((t & 63) == 0) ws[t >> 6] = v;
    __syncthreads();
    if (t == 0) out[0] = (ws[0] + ws[1] + ws[2] + ws[3]) * (1.f / (float)BATCH);
}

extern "C" void kernel_launch(void* const* d_in, const int* in_sizes, int n_in,
                              void* d_out, int out_size, void* d_ws, size_t ws_size,
                              hipStream_t stream) {
    const int*   user_seqs = (const int*)d_in[0];
    const int*   his       = (const int*)d_in[1];
    const int*   next_itm  = (const int*)d_in[2];
    const int*   adj_row   = (const int*)d_in[3];
    const int*   adj_col   = (const int*)d_in[4];
    const float* user_emb  = (const float*)d_in[6];
    const float* item_emb  = (const float*)d_in[7];
    float* out = (float*)d_out;
    int nedges = in_sizes[3];   // 12,800,000

    // Workspace layout (~183 MB)
    unsigned char* w0 = (unsigned char*)d_ws;              // 12.8 MB each
    unsigned char* w1 = w0 + (size_t)N_NODES * D;
    unsigned char* w2 = w1 + (size_t)N_NODES * D;
    unsigned char* w3 = w2 + (size_t)N_NODES * D;
    float*  slabel = (float*)(w3 + (size_t)N_NODES * D);   // 2,048
    float*  sumexp = slabel + BATCH;                       // 2,048   (zeroed)
    int*    gcursor= (int*)(sumexp + BATCH);               // 391     (zeroed)
    int*    rowptr = gcursor + N_BUCKETS;                  // 200,000
    int*    deg    = rowptr + N_NODES;                     // 200,000
    int*    staged = deg + N_NODES;                        // 391*36864 ints (57.7 MB)
    int*    ecols  = staged + (size_t)N_BUCKETS * BCAP;    // 391*36864 ints (57.7 MB)
    ushort* item_bf = (ushort*)(ecols + (size_t)N_BUCKETS * BCAP);  // 100096*64 ushort
    ushort* pred_bf = item_bf + (size_t)N_ITEMS_PAD * D;   // 131072 ushort

    // zero sumexp + gcursor in one shot (contiguous)
    hipError_t _e = hipMemsetAsync(sumexp, 0, (size_t)(BATCH + N_BUCKETS) * sizeof(int), stream);
    (void)_e;

    int nchunks = (nedges + CHUNK - 1) / CHUNK;
    k_binA<<<nchunks, 256, 0, stream>>>(adj_row, adj_col, gcursor, staged, nedges);
    k_binB<<<N_BUCKETS, 512, 0, stream>>>(gcursor, staged, ecols, rowptr, deg,
                                          user_emb, item_emb, w0);

    k_prop<<<N_NODES / 4, 256, 0, stream>>>(rowptr, deg, ecols, w0, w1);
    k_prop<<<N_NODES / 4, 256, 0, stream>>>(rowptr, deg, ecols, w1, w2);
    k_prop<<<N_NODES / 4, 256, 0, stream>>>(rowptr, deg, ecols, w2, w3);

    k_conv_items<<<(N_ITEMS_PAD * (D / 4) + 255) / 256, 256, 0, stream>>>(item_emb, deg, w1, w2, w3, item_bf);
    k_pred<<<BATCH / 4, 256, 0, stream>>>(user_seqs, his, next_itm, user_emb, item_emb, deg,
                                          w1, w2, w3, pred_bf, slabel);

    dim3 gs(ISPLITS, BATCH / 128);
    k_scores<<<gs, 256, 0, stream>>>(item_bf, pred_bf, sumexp);

    k_loss<<<1, 256, 0, stream>>>(sumexp, slabel, out);
}

// Round 8
// 667.124 us; speedup vs baseline: 1.7552x; 1.0358x over previous
//
#include <hip/hip_runtime.h>
#include <hip/hip_bf16.h>
#include <cstddef>

// Problem constants (fixed by reference)
#define N_USERS   100000
#define N_ITEMS   100000
#define N_NODES   200000
#define D         64
#define BATCH     2048
#define HIST      50
#define N_ITEMS_PAD 100096   // padded to multiple of 128 (block item-chunk)

#define BUCKET_SHIFT 9                       // 512 rows per bucket
#define N_BUCKETS_RAW ((N_NODES + 511) >> 9) // 391
#define CHUNK 8192                           // edges per binning block
#define EPT   (CHUNK / 256)                  // 32 edges per thread (8 x int4)
// Fixed bucket capacity: counts ~ Binomial(12.8M, 512/200K): mean 32768, sigma 181.
// 36864 = mean + 22 sigma. Deterministic seed-0 dataset; guarded per-edge anyway.
#define BCAP 36864

// k_scores geometry: batch-stationary waves, item-streaming.
#define ISPLITS 92                           // 100096/32 = 3128 tiles = 92 * 34
#define TPS (N_ITEMS_PAD / 32 / ISPLITS)     // 34 item-tiles per x-block
#define LOG2E 1.44269504088896f

typedef __attribute__((ext_vector_type(8))) short short8;
typedef __attribute__((ext_vector_type(16))) float float16;
typedef __attribute__((ext_vector_type(2)))  float floatx2;

__device__ __forceinline__ float exp2fast(float x) {   // v_exp_f32 = 2^x
    return __builtin_amdgcn_exp2f(x);
}
__device__ __forceinline__ ushort f2bf(float x) {  // fp32 -> bf16 RNE
    unsigned u = __float_as_uint(x);
    return (ushort)((u + 0x7FFF + ((u >> 16) & 1)) >> 16);
}
__device__ __forceinline__ unsigned char f2fp8(float x) {  // fp32 -> fp8 e4m3 (OCP), RNE+sat
    int p = __builtin_amdgcn_cvt_pk_fp8_f32(x, x, 0, false);
    return (unsigned char)(p & 0xFF);
}
__device__ __forceinline__ float fp82f(unsigned char u) {  // fp8 e4m3 -> fp32
    return __builtin_amdgcn_cvt_f32_fp8((int)u, 0);
}

// ---------------- pass A: bin edges into fixed-capacity bucket arenas ----------------
// ONE return-LDS-atomic per edge: claim slot in LDS cursor, stash (slot<<18)|row in
// registers, reserve the block's bucket runs after a barrier, then place records
// (adj_col int4-reloaded, L2-warm). NO global atomics anywhere (R2/R4 lesson:
// per-edge device-scope atomics bypass per-XCD L2 -> 300+ MB memory-side traffic).
__global__ __launch_bounds__(256) void k_binA(const int* __restrict__ adj_row,
                                              const int* __restrict__ adj_col,
                                              int* __restrict__ gcursor, int* __restrict__ staged,
                                              int nedges) {
    __shared__ int cur[N_BUCKETS_RAW];
    __shared__ int lbase[N_BUCKETS_RAW];
    int t = threadIdx.x;
    int base = blockIdx.x * CHUNK;
    for (int i = t; i < N_BUCKETS_RAW; i += 256) cur[i] = 0;
    __syncthreads();
    int stash[EPT];
#pragma unroll
    for (int k = 0; k < EPT / 4; ++k) {
        int e0 = base + (k * 256 + t) * 4;
        if (e0 + 3 < nedges) {
            int4 r4 = *(const int4*)(adj_row + e0);
            int p;
            p = atomicAdd(&cur[r4.x >> BUCKET_SHIFT], 1); stash[4 * k    ] = (p << 18) | r4.x;
            p = atomicAdd(&cur[r4.y >> BUCKET_SHIFT], 1); stash[4 * k + 1] = (p << 18) | r4.y;
            p = atomicAdd(&cur[r4.z >> BUCKET_SHIFT], 1); stash[4 * k + 2] = (p << 18) | r4.z;
            p = atomicAdd(&cur[r4.w >> BUCKET_SHIFT], 1); stash[4 * k + 3] = (p << 18) | r4.w;
        } else {
#pragma unroll
            for (int j = 0; j < 4; ++j) {
                int e = e0 + j;
                if (e < nedges) {
                    int r = adj_row[e];
                    int p = atomicAdd(&cur[r >> BUCKET_SHIFT], 1);
                    stash[4 * k + j] = (p << 18) | r;
                } else stash[4 * k + j] = -1;
            }
        }
    }
    __syncthreads();
    for (int b = t; b < N_BUCKETS_RAW; b += 256) {
        int c = cur[b];
        int s = (c > 0) ? atomicAdd(&gcursor[b], c) : 0;
        lbase[b] = b * BCAP + s;
    }
    __syncthreads();
#pragma unroll
    for (int k = 0; k < EPT / 4; ++k) {
        int e0 = base + (k * 256 + t) * 4;
        if (e0 + 3 < nedges) {
            int4 c4 = *(const int4*)(adj_col + e0);
#pragma unroll
            for (int j = 0; j < 4; ++j) {
                int v = stash[4 * k + j];
                int c = (j == 0) ? c4.x : (j == 1) ? c4.y : (j == 2) ? c4.z : c4.w;
                int r = v & 0x3FFFF;
                int b = r >> BUCKET_SHIFT;
                int pos = lbase[b] + (v >> 18);
                if (pos < (b + 1) * BCAP)             // overflow guard (never fires)
                    staged[pos] = ((r & 511) << 18) | c;
            }
        } else {
#pragma unroll
            for (int j = 0; j < 4; ++j) {
                int v = stash[4 * k + j];
                if (v >= 0) {
                    int e = e0 + j;
                    int c = adj_col[e];
                    int r = v & 0x3FFFF;
                    int b = r >> BUCKET_SHIFT;
                    int pos = lbase[b] + (v >> 18);
                    if (pos < (b + 1) * BCAP)
                        staged[pos] = ((r & 511) << 18) | c;
                }
            }
        }
    }
}

// ---------------- pass B: per bucket, LDS count+scan -> packed ecols/rowptr/deg; fused init ----------------
// 512 threads: thread t owns row t of the bucket. Also computes
// w0 = fp8(64 * x0 / sqrt(max(deg,1))) for the bucket's 512 rows (init fused).
__global__ __launch_bounds__(512) void k_binB(const int* __restrict__ gcursor, const int* __restrict__ staged,
                                              int* __restrict__ ecols, int* __restrict__ rowptr,
                                              int* __restrict__ deg,
                                              const float* __restrict__ user_emb,
                                              const float* __restrict__ item_emb,
                                              unsigned char* __restrict__ w0) {
    __shared__ int cnt[512];
    __shared__ int scn[512];
    __shared__ int cur[512];
    int b = blockIdx.x, t = threadIdx.x;
    cnt[t] = 0;
    __syncthreads();
    int nb = gcursor[b]; if (nb > BCAP) nb = BCAP;
    size_t es = (size_t)b * BCAP;
    for (int e = t; e < nb; e += 512) atomicAdd(&cnt[staged[es + e] >> 18], 1);
    __syncthreads();
    int myc = cnt[t];
    scn[t] = myc;
    __syncthreads();
    for (int off = 1; off < 512; off <<= 1) {
        int v = (t >= off) ? scn[t - off] : 0;
        __syncthreads();
        scn[t] += v;
        __syncthreads();
    }
    int excl = scn[t] - myc;
    int r = (b << BUCKET_SHIFT) + t;
    int gpos = b * BCAP + excl;
    if (r < N_NODES) { rowptr[r] = gpos; deg[r] = myc; }
    cur[t] = gpos;
    __syncthreads();
    for (int e = t; e < nb; e += 512) {
        int v = staged[es + e];
        int pos = atomicAdd(&cur[v >> 18], 1);
        ecols[pos] = (v & 0x3FFFF) << 6;   // byte offset into fp8 node rows
    }
    // fused init for this bucket's rows (cnt[] is stable; cur/scn unused here)
    int r0 = b << BUCKET_SHIFT;
    for (int f = t; f < 512 * 16; f += 512) {
        int lr = f >> 4;
        int row = r0 + lr;
        if (row >= N_NODES) continue;
        const float4* src = (row < N_USERS)
            ? ((const float4*)user_emb) + (size_t)row * 16 + (f & 15)
            : ((const float4*)item_emb) + (size_t)(row - (N_USERS - 1)) * 16 + (f & 15);
        float4 v = *src;
        int dg = cnt[lr]; if (dg < 1) dg = 1;
        float sc = 64.f * __frsqrt_rn((float)dg);
        uchar4 o;
        o.x = f2fp8(v.x * sc); o.y = f2fp8(v.y * sc);
        o.z = f2fp8(v.z * sc); o.w = f2fp8(v.w * sc);
        ((uchar4*)w0)[(size_t)row * 16 + (f & 15)] = o;
    }
}

// ---------------- propagate (fp8 z-space): w_out[r] = (1/deg_r) * sum w_in[c] ----------------
// 8 lanes/edge x dwordx2 gathers; packed cvt + v_pk_add_f32 accumulators.
#define ACC8(v)                                               \
    a01 += __builtin_amdgcn_cvt_pk_f32_fp8((int)(v).x, false); \
    a23 += __builtin_amdgcn_cvt_pk_f32_fp8((int)(v).x, true);  \
    a45 += __builtin_amdgcn_cvt_pk_f32_fp8((int)(v).y, false); \
    a67 += __builtin_amdgcn_cvt_pk_f32_fp8((int)(v).y, true);

__global__ __launch_bounds__(256) void k_prop(const int* __restrict__ rowptr, const int* __restrict__ deg,
                                              const int* __restrict__ ecols,
                                              const unsigned char* __restrict__ x_in,
                                              unsigned char* __restrict__ x_out) {
    int w = blockIdx.x * 4 + (threadIdx.x >> 6);
    int lane = threadIdx.x & 63;
    int slot = lane >> 3;          // one of 8 edge slots
    int d8 = (lane & 7) * 8;       // 8 dims per lane
    int s = rowptr[w];
    int cnt = deg[w];
    const int* ec = ecols + s;
    floatx2 a01 = {0.f, 0.f}, a23 = {0.f, 0.f}, a45 = {0.f, 0.f}, a67 = {0.f, 0.f};
    int p = 0;
    for (; p + 64 <= cnt; p += 64) {
        int c0 = ec[p + slot];
        int c1 = ec[p + 8 + slot];
        int c2 = ec[p + 16 + slot];
        int c3 = ec[p + 24 + slot];
        int c4 = ec[p + 32 + slot];
        int c5 = ec[p + 40 + slot];
        int c6 = ec[p + 48 + slot];
        int c7 = ec[p + 56 + slot];
        uint2 v0 = *(const uint2*)(x_in + c0 + d8);
        uint2 v1 = *(const uint2*)(x_in + c1 + d8);
        uint2 v2 = *(const uint2*)(x_in + c2 + d8);
        uint2 v3 = *(const uint2*)(x_in + c3 + d8);
        uint2 v4 = *(const uint2*)(x_in + c4 + d8);
        uint2 v5 = *(const uint2*)(x_in + c5 + d8);
        uint2 v6 = *(const uint2*)(x_in + c6 + d8);
        uint2 v7 = *(const uint2*)(x_in + c7 + d8);
        ACC8(v0) ACC8(v1) ACC8(v2) ACC8(v3)
        ACC8(v4) ACC8(v5) ACC8(v6) ACC8(v7)
    }
    for (; p + 32 <= cnt; p += 32) {
        int c0 = ec[p + slot];
        int c1 = ec[p + 8 + slot];
        int c2 = ec[p + 16 + slot];
        int c3 = ec[p + 24 + slot];
        uint2 v0 = *(const uint2*)(x_in + c0 + d8);
        uint2 v1 = *(const uint2*)(x_in + c1 + d8);
        uint2 v2 = *(const uint2*)(x_in + c2 + d8);
        uint2 v3 = *(const uint2*)(x_in + c3 + d8);
        ACC8(v0) ACC8(v1) ACC8(v2) ACC8(v3)
    }
    for (; p < cnt; p += 8) {
        int rem = cnt - p;                     // >= 1
        int sl = (slot < rem) ? slot : 0;
        int c = ec[p + sl];
        uint2 v = *(const uint2*)(x_in + c + d8);
        if (slot < rem) { ACC8(v) }
    }
    // cross-slot reduce: lanes L, L+8, ..., L+56 hold same dims, different edges
#pragma unroll
    for (int off = 32; off >= 8; off >>= 1) {
        a01.x += __shfl_down(a01.x, off); a01.y += __shfl_down(a01.y, off);
        a23.x += __shfl_down(a23.x, off); a23.y += __shfl_down(a23.y, off);
        a45.x += __shfl_down(a45.x, off); a45.y += __shfl_down(a45.y, off);
        a67.x += __shfl_down(a67.x, off); a67.y += __shfl_down(a67.y, off);
    }
    if (lane < 8) {
        float inv = (cnt > 0) ? 1.f / (float)cnt : 0.f;
        int w01 = __builtin_amdgcn_cvt_pk_fp8_f32(a01.x * inv, a01.y * inv, 0, false);
        w01     = __builtin_amdgcn_cvt_pk_fp8_f32(a23.x * inv, a23.y * inv, w01, true);
        int w23 = __builtin_amdgcn_cvt_pk_fp8_f32(a45.x * inv, a45.y * inv, 0, false);
        w23     = __builtin_amdgcn_cvt_pk_fp8_f32(a67.x * inv, a67.y * inv, w23, true);
        uint2 o; o.x = (unsigned)w01; o.y = (unsigned)w23;
        *(uint2*)(x_out + (size_t)w * D + d8) = o;
    }
}

// ---------------- item latents, fragment-tiled + log2e-scaled ----------------
// out value = LOG2E * bf16(0.25*item_emb + sqrt(deg)/256*(w1+w2+w3)); zero-pad rows.
// Layout: tile = row>>5 (32 rows); within tile, address [q][lane][8elems]:
//   lane = (row&31) + 32*half, dim = q*16 + half*8 + e  (q=0..3, half=0..1, e=0..7)
// -> a wave's MFMA A-frag load in k_scores is base + lane*16B: one 1KB coalesced load.
__global__ void k_conv_items(const float* __restrict__ item_emb, const int* __restrict__ deg,
                             const unsigned char* __restrict__ w1, const unsigned char* __restrict__ w2,
                             const unsigned char* __restrict__ w3, ushort* __restrict__ item_bf) {
    int f = blockIdx.x * 256 + threadIdx.x;    // one 4-dim group
    if (f >= N_ITEMS_PAD * (D / 4)) return;
    int row = f >> 4, c4 = f & 15;
    ushort4 o;
    if (row < N_ITEMS) {
        int node = N_USERS + row;
        int dg = deg[node]; if (dg < 1) dg = 1;
        float s = sqrtf((float)dg) * (1.f / 256.f);    // sqrt(deg)/(64 scale * 4 avg)
        float4 e4 = ((const float4*)(item_emb + (size_t)(row + 1) * D))[c4];
        size_t n4 = (size_t)node * 16 + c4;
        uchar4 a = ((const uchar4*)w1)[n4];
        uchar4 b = ((const uchar4*)w2)[n4];
        uchar4 c = ((const uchar4*)w3)[n4];
        o.x = f2bf(LOG2E * (0.25f * e4.x + s * (fp82f(a.x) + fp82f(b.x) + fp82f(c.x))));
        o.y = f2bf(LOG2E * (0.25f * e4.y + s * (fp82f(a.y) + fp82f(b.y) + fp82f(c.y))));
        o.z = f2bf(LOG2E * (0.25f * e4.z + s * (fp82f(a.z) + fp82f(b.z) + fp82f(c.z))));
        o.w = f2bf(LOG2E * (0.25f * e4.w + s * (fp82f(a.w) + fp82f(b.w) + fp82f(c.w))));
    } else {
        o.x = o.y = o.z = o.w = 0;   // pad rows -> score 0 -> exp2 = 1 (subtract 96 in k_loss)
    }
    int tile = row >> 5, rr = row & 31;
    int q = c4 >> 2, half = (c4 >> 1) & 1, e0 = (c4 & 1) * 4;
    size_t idx = (size_t)tile * 2048 + q * 512 + (rr + 32 * half) * 8 + e0;
    *(ushort4*)(item_bf + idx) = o;
}

// ---------------- pred (bf16 copy) + label score ----------------
__global__ __launch_bounds__(256) void k_pred(const int* __restrict__ user_seqs, const int* __restrict__ his,
                                              const int* __restrict__ next_items,
                                              const float* __restrict__ user_emb, const float* __restrict__ item_emb,
                                              const int* __restrict__ deg,
                                              const unsigned char* __restrict__ w1, const unsigned char* __restrict__ w2,
                                              const unsigned char* __restrict__ w3,
                                              ushort* __restrict__ pred_bf, float* __restrict__ slabel) {
    int b = blockIdx.x * 4 + (threadIdx.x >> 6);
    int lane = threadIdx.x & 63;
    int u = user_seqs[b];
    float hsum = 0.f; int cnt = 0;
    for (int j = 0; j < HIST; ++j) {
        int it = his[b * HIST + j];
        cnt += (it != 0);
        hsum += item_emb[(size_t)it * D + lane];   // item_emb[0] is all-zero (pad)
    }
    int du = deg[u]; if (du < 1) du = 1;
    float su = sqrtf((float)du) * (1.f / 256.f);
    size_t ur = (size_t)u * D + lane;
    float ulat = 0.25f * user_emb[ur] + su * (fp82f(w1[ur]) + fp82f(w2[ur]) + fp82f(w3[ur]));
    float pv = ulat + hsum / (float)cnt;
    pred_bf[(size_t)b * D + lane] = f2bf(pv);
    int lab = next_items[b] - 1;
    int node = N_USERS + lab;
    int di = deg[node]; if (di < 1) di = 1;
    float si = sqrtf((float)di) * (1.f / 256.f);
    size_t nr = (size_t)node * D + lane;
    float ilat = 0.25f * item_emb[(size_t)(lab + 1) * D + lane]
               + si * (fp82f(w1[nr]) + fp82f(w2[nr]) + fp82f(w3[nr]));
    float tv = pv * ilat;
#pragma unroll
    for (int off = 32; off > 0; off >>= 1) tv += __shfl_down(tv, off);
    if (lane == 0) slabel[b] = tv;
}

// ---------------- MFMA scores + max-free sumexp (batch-stationary, frag-tiled items) ----------------
// Item frags stream as coalesced lane*16B loads; register double-buffer prefetch of
// the next tile-pair hides L2 latency under MFMA+exp of the current pair.
#define MFMA __builtin_amdgcn_mfma_f32_32x32x16_bf16
__global__ __launch_bounds__(256) void k_scores(const ushort* __restrict__ item_bf,
                                                const ushort* __restrict__ pred_bf,
                                                float* __restrict__ sumexp) {
    int t = threadIdx.x, wv = t >> 6, lane = t & 63;
    int l31 = lane & 31;
    int khalf = (lane >> 5) * 8;   // which 8-elem k-half this lane holds

    int brow = blockIdx.y * 128 + wv * 32 + l31;        // this lane's batch column
    const ushort* pb = pred_bf + (size_t)brow * D + khalf;
    short8 b0 = *(const short8*)(pb);
    short8 b1 = *(const short8*)(pb + 16);
    short8 b2 = *(const short8*)(pb + 32);
    short8 b3 = *(const short8*)(pb + 48);

    const ushort* ib = item_bf + (size_t)blockIdx.x * TPS * 2048 + lane * 8;
    float acc = 0.f;

    short8 x0 = *(const short8*)(ib);
    short8 x1 = *(const short8*)(ib + 512);
    short8 x2 = *(const short8*)(ib + 1024);
    short8 x3 = *(const short8*)(ib + 1536);
    short8 x4 = *(const short8*)(ib + 2048);
    short8 x5 = *(const short8*)(ib + 2560);
    short8 x6 = *(const short8*)(ib + 3072);
    short8 x7 = *(const short8*)(ib + 3584);

    for (int tt = 0; tt < TPS; tt += 2) {
        // prefetch next pair (last iteration reads 8KB past this split's tiles —
        // lands in the next split / pred_bf region, valid memory, never used)
        const ushort* in = ib + (size_t)(tt + 2) * 2048;
        short8 y0 = *(const short8*)(in);
        short8 y1 = *(const short8*)(in + 512);
        short8 y2 = *(const short8*)(in + 1024);
        short8 y3 = *(const short8*)(in + 1536);
        short8 y4 = *(const short8*)(in + 2048);
        short8 y5 = *(const short8*)(in + 2560);
        short8 y6 = *(const short8*)(in + 3072);
        short8 y7 = *(const short8*)(in + 3584);
        float16 c0 = {0.f};
        float16 c1 = {0.f};
        c0 = MFMA(x0, b0, c0, 0, 0, 0);
        c1 = MFMA(x4, b0, c1, 0, 0, 0);
        c0 = MFMA(x1, b1, c0, 0, 0, 0);
        c1 = MFMA(x5, b1, c1, 0, 0, 0);
        c0 = MFMA(x2, b2, c0, 0, 0, 0);
        c1 = MFMA(x6, b2, c1, 0, 0, 0);
        c0 = MFMA(x3, b3, c0, 0, 0, 0);
        c1 = MFMA(x7, b3, c1, 0, 0, 0);
        float s0 = 0.f, s1 = 0.f, s2 = 0.f, s3 = 0.f;
#pragma unroll
        for (int r = 0; r < 16; r += 4) {
            s0 += exp2fast(c0[r]);
            s1 += exp2fast(c0[r + 1]);
            s2 += exp2fast(c0[r + 2]);
            s3 += exp2fast(c0[r + 3]);
        }
#pragma unroll
        for (int r = 0; r < 16; r += 4) {
            s0 += exp2fast(c1[r]);
            s1 += exp2fast(c1[r + 1]);
            s2 += exp2fast(c1[r + 2]);
            s3 += exp2fast(c1[r + 3]);
        }
        acc += (s0 + s1) + (s2 + s3);
        x0 = y0; x1 = y1; x2 = y2; x3 = y3;
        x4 = y4; x5 = y5; x6 = y6; x7 = y7;
    }
    // lane L and L+32 hold the two item-row halves of the same batch col
    acc += __shfl_down(acc, 32);
    if (lane < 32) unsafeAtomicAdd(&sumexp[brow], acc);
}

// ---------------- final loss reduce ----------------
__global__ __launch_bounds__(256) void k_loss(const float* __restrict__ sumexp, const float* __restrict__ slabel,
                                              float* __restrict__ out) {
    __shared__ float ws[4];
    int t = threadIdx.x;
    float v = 0.f;
    for (int i = t; i < BATCH; i += 256)
        v += __logf(sumexp[i] - 96.0f) - slabel[i];   // -96: padded items contribute exp2(0)=1 each
#pragma unroll
    for (int off = 32; off > 0; off >>= 1) v += __shfl_down(v, off);
    if ((t & 63) == 0) ws[t >> 6] = v;
    __syncthreads();
    if (t == 0) out[0] = (ws[0] + ws[1] + ws[2] + ws[3]) * (1.f / (float)BATCH);
}

extern "C" void kernel_launch(void* const* d_in, const int* in_sizes, int n_in,
                              void* d_out, int out_size, void* d_ws, size_t ws_size,
                              hipStream_t stream) {
    const int*   user_seqs = (const int*)d_in[0];
    const int*   his       = (const int*)d_in[1];
    const int*   next_itm  = (const int*)d_in[2];
    const int*   adj_row   = (const int*)d_in[3];
    const int*   adj_col   = (const int*)d_in[4];
    const float* user_emb  = (const float*)d_in[6];
    const float* item_emb  = (const float*)d_in[7];
    float* out = (float*)d_out;
    int nedges = in_sizes[3];   // 12,800,000

    // Workspace layout (~183 MB). gcursor padded to 512 ints so every downstream
    // buffer stays 256B-aligned (item_bf/pred_bf short8 loads need 16B alignment;
    // previously item_bf sat at byte%16==12 -> every dwordx4 split in two).
    unsigned char* w0 = (unsigned char*)d_ws;              // 12.8 MB each
    unsigned char* w1 = w0 + (size_t)N_NODES * D;
    unsigned char* w2 = w1 + (size_t)N_NODES * D;
    unsigned char* w3 = w2 + (size_t)N_NODES * D;
    float*  slabel = (float*)(w3 + (size_t)N_NODES * D);   // 2,048
    float*  sumexp = slabel + BATCH;                       // 2,048   (zeroed)
    int*    gcursor= (int*)(sumexp + BATCH);               // 512 (zeroed; 391 used)
    int*    rowptr = gcursor + 512;                        // 200,000
    int*    deg    = rowptr + N_NODES;                     // 200,000
    int*    staged = deg + N_NODES;                        // 391*36864 ints (57.7 MB)
    int*    ecols  = staged + (size_t)N_BUCKETS_RAW * BCAP; // 391*36864 ints (57.7 MB)
    ushort* item_bf = (ushort*)(ecols + (size_t)N_BUCKETS_RAW * BCAP);  // 100096*64 ushort, 256B-aligned
    ushort* pred_bf = item_bf + (size_t)N_ITEMS_PAD * D;   // 131072 ushort

    // zero sumexp + gcursor in one shot (contiguous)
    hipError_t _e = hipMemsetAsync(sumexp, 0, (size_t)(BATCH + 512) * sizeof(int), stream);
    (void)_e;

    int nchunks = (nedges + CHUNK - 1) / CHUNK;
    k_binA<<<nchunks, 256, 0, stream>>>(adj_row, adj_col, gcursor, staged, nedges);
    k_binB<<<N_BUCKETS_RAW, 512, 0, stream>>>(gcursor, staged, ecols, rowptr, deg,
                                              user_emb, item_emb, w0);

    k_prop<<<N_NODES / 4, 256, 0, stream>>>(rowptr, deg, ecols, w0, w1);
    k_prop<<<N_NODES / 4, 256, 0, stream>>>(rowptr, deg, ecols, w1, w2);
    k_prop<<<N_NODES / 4, 256, 0, stream>>>(rowptr, deg, ecols, w2, w3);

    k_conv_items<<<(N_ITEMS_PAD * (D / 4) + 255) / 256, 256, 0, stream>>>(item_emb, deg, w1, w2, w3, item_bf);
    k_pred<<<BATCH / 4, 256, 0, stream>>>(user_seqs, his, next_itm, user_emb, item_emb, deg,
                                          w1, w2, w3, pred_bf, slabel);

    dim3 gs(ISPLITS, BATCH / 128);
    k_scores<<<gs, 256, 0, stream>>>(item_bf, pred_bf, sumexp);

    k_loss<<<1, 256, 0, stream>>>(sumexp, slabel, out);
}

// Round 9
// 631.815 us; speedup vs baseline: 1.8533x; 1.0559x over previous
//
#include <hip/hip_runtime.h>
#include <hip/hip_bf16.h>
#include <cstddef>

// Problem constants (fixed by reference)
#define N_USERS   100000
#define N_ITEMS   100000
#define N_NODES   200000
#define D         64
#define BATCH     2048
#define HIST      50
#define N_ITEMS_PAD 100096   // padded to multiple of 128 (block item-chunk)

#define BUCKET_SHIFT 9                       // 512 rows per bucket
#define N_BUCKETS_RAW ((N_NODES + 511) >> 9) // 391
#define CHUNK 8192                           // edges per binning block
#define EPT   (CHUNK / 256)                  // 32 edges per thread (8 x int4)
// Fixed bucket capacity: counts ~ Binomial(12.8M, 512/200K): mean 32768, sigma 181.
// 36864 = mean + 22 sigma. Deterministic seed-0 dataset; guarded per-edge anyway.
#define BCAP 36864

// k_scores geometry: batch-stationary waves, item-streaming.
#define ISPLITS 92                           // 100096/32 = 3128 tiles = 92 * 34
#define TPS (N_ITEMS_PAD / 32 / ISPLITS)     // 34 item-tiles per x-block
#define LOG2E 1.44269504088896f

typedef __attribute__((ext_vector_type(8))) short short8;
typedef __attribute__((ext_vector_type(16))) float float16;
typedef __attribute__((ext_vector_type(2)))  float floatx2;

__device__ __forceinline__ float exp2fast(float x) {   // v_exp_f32 = 2^x
    return __builtin_amdgcn_exp2f(x);
}
__device__ __forceinline__ ushort f2bf(float x) {  // fp32 -> bf16 RNE
    unsigned u = __float_as_uint(x);
    return (ushort)((u + 0x7FFF + ((u >> 16) & 1)) >> 16);
}
__device__ __forceinline__ unsigned char f2fp8(float x) {  // fp32 -> fp8 e4m3 (OCP), RNE+sat
    int p = __builtin_amdgcn_cvt_pk_fp8_f32(x, x, 0, false);
    return (unsigned char)(p & 0xFF);
}
__device__ __forceinline__ float fp82f(unsigned char u) {  // fp8 e4m3 -> fp32
    return __builtin_amdgcn_cvt_f32_fp8((int)u, 0);
}

// ---------------- pass A: bin edges into fixed-capacity bucket arenas ----------------
// ONE return-LDS-atomic per edge: claim slot in LDS cursor, stash (slot<<18)|row in
// registers, reserve the block's bucket runs after a barrier, then place records
// (adj_col int4-reloaded, L2-warm). NO global atomics anywhere (R2/R4 lesson:
// per-edge device-scope atomics bypass per-XCD L2 -> 300+ MB memory-side traffic).
__global__ __launch_bounds__(256) void k_binA(const int* __restrict__ adj_row,
                                              const int* __restrict__ adj_col,
                                              int* __restrict__ gcursor, int* __restrict__ staged,
                                              int nedges) {
    __shared__ int cur[N_BUCKETS_RAW];
    __shared__ int lbase[N_BUCKETS_RAW];
    int t = threadIdx.x;
    int base = blockIdx.x * CHUNK;
    for (int i = t; i < N_BUCKETS_RAW; i += 256) cur[i] = 0;
    __syncthreads();
    int stash[EPT];
#pragma unroll
    for (int k = 0; k < EPT / 4; ++k) {
        int e0 = base + (k * 256 + t) * 4;
        if (e0 + 3 < nedges) {
            int4 r4 = *(const int4*)(adj_row + e0);
            int p;
            p = atomicAdd(&cur[r4.x >> BUCKET_SHIFT], 1); stash[4 * k    ] = (p << 18) | r4.x;
            p = atomicAdd(&cur[r4.y >> BUCKET_SHIFT], 1); stash[4 * k + 1] = (p << 18) | r4.y;
            p = atomicAdd(&cur[r4.z >> BUCKET_SHIFT], 1); stash[4 * k + 2] = (p << 18) | r4.z;
            p = atomicAdd(&cur[r4.w >> BUCKET_SHIFT], 1); stash[4 * k + 3] = (p << 18) | r4.w;
        } else {
#pragma unroll
            for (int j = 0; j < 4; ++j) {
                int e = e0 + j;
                if (e < nedges) {
                    int r = adj_row[e];
                    int p = atomicAdd(&cur[r >> BUCKET_SHIFT], 1);
                    stash[4 * k + j] = (p << 18) | r;
                } else stash[4 * k + j] = -1;
            }
        }
    }
    __syncthreads();
    for (int b = t; b < N_BUCKETS_RAW; b += 256) {
        int c = cur[b];
        int s = (c > 0) ? atomicAdd(&gcursor[b], c) : 0;
        lbase[b] = b * BCAP + s;
    }
    __syncthreads();
#pragma unroll
    for (int k = 0; k < EPT / 4; ++k) {
        int e0 = base + (k * 256 + t) * 4;
        if (e0 + 3 < nedges) {
            int4 c4 = *(const int4*)(adj_col + e0);
#pragma unroll
            for (int j = 0; j < 4; ++j) {
                int v = stash[4 * k + j];
                int c = (j == 0) ? c4.x : (j == 1) ? c4.y : (j == 2) ? c4.z : c4.w;
                int r = v & 0x3FFFF;
                int b = r >> BUCKET_SHIFT;
                int pos = lbase[b] + (v >> 18);
                if (pos < (b + 1) * BCAP)             // overflow guard (never fires)
                    staged[pos] = ((r & 511) << 18) | c;
            }
        } else {
#pragma unroll
            for (int j = 0; j < 4; ++j) {
                int v = stash[4 * k + j];
                if (v >= 0) {
                    int e = e0 + j;
                    int c = adj_col[e];
                    int r = v & 0x3FFFF;
                    int b = r >> BUCKET_SHIFT;
                    int pos = lbase[b] + (v >> 18);
                    if (pos < (b + 1) * BCAP)
                        staged[pos] = ((r & 511) << 18) | c;
                }
            }
        }
    }
}

// ---------------- pass B: per bucket, LDS count+scan -> packed ecols/rowptr/deg; fused init ----------------
__global__ __launch_bounds__(512) void k_binB(const int* __restrict__ gcursor, const int* __restrict__ staged,
                                              int* __restrict__ ecols, int* __restrict__ rowptr,
                                              int* __restrict__ deg,
                                              const float* __restrict__ user_emb,
                                              const float* __restrict__ item_emb,
                                              unsigned char* __restrict__ w0) {
    __shared__ int cnt[512];
    __shared__ int scn[512];
    __shared__ int cur[512];
    int b = blockIdx.x, t = threadIdx.x;
    cnt[t] = 0;
    __syncthreads();
    int nb = gcursor[b]; if (nb > BCAP) nb = BCAP;
    size_t es = (size_t)b * BCAP;
    for (int e = t; e < nb; e += 512) atomicAdd(&cnt[staged[es + e] >> 18], 1);
    __syncthreads();
    int myc = cnt[t];
    scn[t] = myc;
    __syncthreads();
    for (int off = 1; off < 512; off <<= 1) {
        int v = (t >= off) ? scn[t - off] : 0;
        __syncthreads();
        scn[t] += v;
        __syncthreads();
    }
    int excl = scn[t] - myc;
    int r = (b << BUCKET_SHIFT) + t;
    int gpos = b * BCAP + excl;
    if (r < N_NODES) { rowptr[r] = gpos; deg[r] = myc; }
    cur[t] = gpos;
    __syncthreads();
    for (int e = t; e < nb; e += 512) {
        int v = staged[es + e];
        int pos = atomicAdd(&cur[v >> 18], 1);
        ecols[pos] = (v & 0x3FFFF) << 6;   // byte offset into fp8 node rows
    }
    // fused init for this bucket's rows (cnt[] is stable; cur/scn unused here)
    int r0 = b << BUCKET_SHIFT;
    for (int f = t; f < 512 * 16; f += 512) {
        int lr = f >> 4;
        int row = r0 + lr;
        if (row >= N_NODES) continue;
        const float4* src = (row < N_USERS)
            ? ((const float4*)user_emb) + (size_t)row * 16 + (f & 15)
            : ((const float4*)item_emb) + (size_t)(row - (N_USERS - 1)) * 16 + (f & 15);
        float4 v = *src;
        int dg = cnt[lr]; if (dg < 1) dg = 1;
        float sc = 64.f * __frsqrt_rn((float)dg);
        uchar4 o;
        o.x = f2fp8(v.x * sc); o.y = f2fp8(v.y * sc);
        o.z = f2fp8(v.z * sc); o.w = f2fp8(v.w * sc);
        ((uchar4*)w0)[(size_t)row * 16 + (f & 15)] = o;
    }
}

// ---------------- propagate (fp8 z-space): w_out[r] = (1/deg_r) * sum w_in[c] ----------------
// v3: group-per-row layout. Wave = 8 rows x 8 dim-lanes; each 8-lane group owns one
// row and iterates its edges serially -> accumulator is dim-stationary, so there is
// NO cross-lane reduce (zero shfl; the old 24-shfl DS chain was ~45% of issued work).
// Gather shape unchanged: per instruction 8 distinct 64B rows, fully-used lines.
// Bulk loop runs unguarded to the wave-min degree (MLP: 4 gathers in flight);
// clamp+cndmask tail to the wave-max degree (max of 8 Poisson(64) ~ 84).
#define ACC8(v)                                               \
    a01 += __builtin_amdgcn_cvt_pk_f32_fp8((int)(v).x, false); \
    a23 += __builtin_amdgcn_cvt_pk_f32_fp8((int)(v).x, true);  \
    a45 += __builtin_amdgcn_cvt_pk_f32_fp8((int)(v).y, false); \
    a67 += __builtin_amdgcn_cvt_pk_f32_fp8((int)(v).y, true);

__global__ __launch_bounds__(256) void k_prop(const int* __restrict__ rowptr, const int* __restrict__ deg,
                                              const int* __restrict__ ecols,
                                              const unsigned char* __restrict__ x_in,
                                              unsigned char* __restrict__ x_out) {
    int lane = threadIdx.x & 63;
    int row = blockIdx.x * 32 + (threadIdx.x >> 6) * 8 + (lane >> 3);
    int d8 = (lane & 7) * 8;       // 8 dims per lane
    int s = rowptr[row];
    int cnt = deg[row];
    const int* ec = ecols + s;
    const unsigned char* xb = x_in + d8;
    // wave-wide min/max of cnt across the 8 row-groups
    int cmin = cnt, cmax = cnt;
#pragma unroll
    for (int off = 8; off < 64; off <<= 1) {
        cmin = min(cmin, __shfl_xor(cmin, off));
        cmax = max(cmax, __shfl_xor(cmax, off));
    }
    floatx2 a01 = {0.f, 0.f}, a23 = {0.f, 0.f}, a45 = {0.f, 0.f}, a67 = {0.f, 0.f};
    int e = 0;
    int bulk = cmin & ~3;
    for (; e < bulk; e += 4) {       // unguarded bulk: 4 gathers in flight
        int c0 = ec[e];
        int c1 = ec[e + 1];
        int c2 = ec[e + 2];
        int c3 = ec[e + 3];
        uint2 v0 = *(const uint2*)(xb + c0);
        uint2 v1 = *(const uint2*)(xb + c1);
        uint2 v2 = *(const uint2*)(xb + c2);
        uint2 v3 = *(const uint2*)(xb + c3);
        ACC8(v0) ACC8(v1) ACC8(v2) ACC8(v3)
    }
    for (; e < cmax; e += 2) {       // clamp+cndmask tail (group-uniform predicates)
        bool k0 = e < cnt, k1 = e + 1 < cnt;
        int c0 = ec[k0 ? e : 0];
        int c1 = ec[k1 ? e + 1 : 0];
        uint2 v0 = *(const uint2*)(xb + c0);
        uint2 v1 = *(const uint2*)(xb + c1);
        v0.x = k0 ? v0.x : 0u; v0.y = k0 ? v0.y : 0u;
        v1.x = k1 ? v1.x : 0u; v1.y = k1 ? v1.y : 0u;
        ACC8(v0) ACC8(v1)
    }
    float inv = (cnt > 0) ? 1.f / (float)cnt : 0.f;
    int w01 = __builtin_amdgcn_cvt_pk_fp8_f32(a01.x * inv, a01.y * inv, 0, false);
    w01     = __builtin_amdgcn_cvt_pk_fp8_f32(a23.x * inv, a23.y * inv, w01, true);
    int w23 = __builtin_amdgcn_cvt_pk_fp8_f32(a45.x * inv, a45.y * inv, 0, false);
    w23     = __builtin_amdgcn_cvt_pk_fp8_f32(a67.x * inv, a67.y * inv, w23, true);
    uint2 o; o.x = (unsigned)w01; o.y = (unsigned)w23;
    *(uint2*)(x_out + (size_t)row * D + d8) = o;   // 64B/row, contiguous per wave
}

// ---------------- item latents, fragment-tiled + log2e-scaled ----------------
// out value = LOG2E * bf16(0.25*item_emb + sqrt(deg)/256*(w1+w2+w3)); zero-pad rows.
// Layout: tile = row>>5 (32 rows); within tile, address [q][lane][8elems]:
//   lane = (row&31) + 32*half, dim = q*16 + half*8 + e  (q=0..3, half=0..1, e=0..7)
// -> a wave's MFMA A-frag load in k_scores is base + lane*16B: one 1KB coalesced load.
__global__ void k_conv_items(const float* __restrict__ item_emb, const int* __restrict__ deg,
                             const unsigned char* __restrict__ w1, const unsigned char* __restrict__ w2,
                             const unsigned char* __restrict__ w3, ushort* __restrict__ item_bf) {
    int f = blockIdx.x * 256 + threadIdx.x;    // one 4-dim group
    if (f >= N_ITEMS_PAD * (D / 4)) return;
    int row = f >> 4, c4 = f & 15;
    ushort4 o;
    if (row < N_ITEMS) {
        int node = N_USERS + row;
        int dg = deg[node]; if (dg < 1) dg = 1;
        float s = sqrtf((float)dg) * (1.f / 256.f);    // sqrt(deg)/(64 scale * 4 avg)
        float4 e4 = ((const float4*)(item_emb + (size_t)(row + 1) * D))[c4];
        size_t n4 = (size_t)node * 16 + c4;
        uchar4 a = ((const uchar4*)w1)[n4];
        uchar4 b = ((const uchar4*)w2)[n4];
        uchar4 c = ((const uchar4*)w3)[n4];
        o.x = f2bf(LOG2E * (0.25f * e4.x + s * (fp82f(a.x) + fp82f(b.x) + fp82f(c.x))));
        o.y = f2bf(LOG2E * (0.25f * e4.y + s * (fp82f(a.y) + fp82f(b.y) + fp82f(c.y))));
        o.z = f2bf(LOG2E * (0.25f * e4.z + s * (fp82f(a.z) + fp82f(b.z) + fp82f(c.z))));
        o.w = f2bf(LOG2E * (0.25f * e4.w + s * (fp82f(a.w) + fp82f(b.w) + fp82f(c.w))));
    } else {
        o.x = o.y = o.z = o.w = 0;   // pad rows -> score 0 -> exp2 = 1 (subtract 96 in k_loss)
    }
    int tile = row >> 5, rr = row & 31;
    int q = c4 >> 2, half = (c4 >> 1) & 1, e0 = (c4 & 1) * 4;
    size_t idx = (size_t)tile * 2048 + q * 512 + (rr + 32 * half) * 8 + e0;
    *(ushort4*)(item_bf + idx) = o;
}

// ---------------- pred (bf16 copy) + label score ----------------
__global__ __launch_bounds__(256) void k_pred(const int* __restrict__ user_seqs, const int* __restrict__ his,
                                              const int* __restrict__ next_items,
                                              const float* __restrict__ user_emb, const float* __restrict__ item_emb,
                                              const int* __restrict__ deg,
                                              const unsigned char* __restrict__ w1, const unsigned char* __restrict__ w2,
                                              const unsigned char* __restrict__ w3,
                                              ushort* __restrict__ pred_bf, float* __restrict__ slabel) {
    int b = blockIdx.x * 4 + (threadIdx.x >> 6);
    int lane = threadIdx.x & 63;
    int u = user_seqs[b];
    float hsum = 0.f; int cnt = 0;
    for (int j = 0; j < HIST; ++j) {
        int it = his[b * HIST + j];
        cnt += (it != 0);
        hsum += item_emb[(size_t)it * D + lane];   // item_emb[0] is all-zero (pad)
    }
    int du = deg[u]; if (du < 1) du = 1;
    float su = sqrtf((float)du) * (1.f / 256.f);
    size_t ur = (size_t)u * D + lane;
    float ulat = 0.25f * user_emb[ur] + su * (fp82f(w1[ur]) + fp82f(w2[ur]) + fp82f(w3[ur]));
    float pv = ulat + hsum / (float)cnt;
    pred_bf[(size_t)b * D + lane] = f2bf(pv);
    int lab = next_items[b] - 1;
    int node = N_USERS + lab;
    int di = deg[node]; if (di < 1) di = 1;
    float si = sqrtf((float)di) * (1.f / 256.f);
    size_t nr = (size_t)node * D + lane;
    float ilat = 0.25f * item_emb[(size_t)(lab + 1) * D + lane]
               + si * (fp82f(w1[nr]) + fp82f(w2[nr]) + fp82f(w3[nr]));
    float tv = pv * ilat;
#pragma unroll
    for (int off = 32; off > 0; off >>= 1) tv += __shfl_down(tv, off);
    if (lane == 0) slabel[b] = tv;
}

// ---------------- MFMA scores + max-free sumexp (batch-stationary, frag-tiled items) ----------------
#define MFMA __builtin_amdgcn_mfma_f32_32x32x16_bf16
__global__ __launch_bounds__(256) void k_scores(const ushort* __restrict__ item_bf,
                                                const ushort* __restrict__ pred_bf,
                                                float* __restrict__ sumexp) {
    int t = threadIdx.x, wv = t >> 6, lane = t & 63;
    int l31 = lane & 31;
    int khalf = (lane >> 5) * 8;   // which 8-elem k-half this lane holds

    int brow = blockIdx.y * 128 + wv * 32 + l31;        // this lane's batch column
    const ushort* pb = pred_bf + (size_t)brow * D + khalf;
    short8 b0 = *(const short8*)(pb);
    short8 b1 = *(const short8*)(pb + 16);
    short8 b2 = *(const short8*)(pb + 32);
    short8 b3 = *(const short8*)(pb + 48);

    const ushort* ib = item_bf + (size_t)blockIdx.x * TPS * 2048 + lane * 8;
    float acc = 0.f;

    short8 x0 = *(const short8*)(ib);
    short8 x1 = *(const short8*)(ib + 512);
    short8 x2 = *(const short8*)(ib + 1024);
    short8 x3 = *(const short8*)(ib + 1536);
    short8 x4 = *(const short8*)(ib + 2048);
    short8 x5 = *(const short8*)(ib + 2560);
    short8 x6 = *(const short8*)(ib + 3072);
    short8 x7 = *(const short8*)(ib + 3584);

    for (int tt = 0; tt < TPS; tt += 2) {
        // prefetch next pair (last iteration reads 8KB past this split's tiles —
        // lands in the next split / pred_bf region, valid memory, never used)
        const ushort* in = ib + (size_t)(tt + 2) * 2048;
        short8 y0 = *(const short8*)(in);
        short8 y1 = *(const short8*)(in + 512);
        short8 y2 = *(const short8*)(in + 1024);
        short8 y3 = *(const short8*)(in + 1536);
        short8 y4 = *(const short8*)(in + 2048);
        short8 y5 = *(const short8*)(in + 2560);
        short8 y6 = *(const short8*)(in + 3072);
        short8 y7 = *(const short8*)(in + 3584);
        float16 c0 = {0.f};
        float16 c1 = {0.f};
        c0 = MFMA(x0, b0, c0, 0, 0, 0);
        c1 = MFMA(x4, b0, c1, 0, 0, 0);
        c0 = MFMA(x1, b1, c0, 0, 0, 0);
        c1 = MFMA(x5, b1, c1, 0, 0, 0);
        c0 = MFMA(x2, b2, c0, 0, 0, 0);
        c1 = MFMA(x6, b2, c1, 0, 0, 0);
        c0 = MFMA(x3, b3, c0, 0, 0, 0);
        c1 = MFMA(x7, b3, c1, 0, 0, 0);
        float s0 = 0.f, s1 = 0.f, s2 = 0.f, s3 = 0.f;
#pragma unroll
        for (int r = 0; r < 16; r += 4) {
            s0 += exp2fast(c0[r]);
            s1 += exp2fast(c0[r + 1]);
            s2 += exp2fast(c0[r + 2]);
            s3 += exp2fast(c0[r + 3]);
        }
#pragma unroll
        for (int r = 0; r < 16; r += 4) {
            s0 += exp2fast(c1[r]);
            s1 += exp2fast(c1[r + 1]);
            s2 += exp2fast(c1[r + 2]);
            s3 += exp2fast(c1[r + 3]);
        }
        acc += (s0 + s1) + (s2 + s3);
        x0 = y0; x1 = y1; x2 = y2; x3 = y3;
        x4 = y4; x5 = y5; x6 = y6; x7 = y7;
    }
    // lane L and L+32 hold the two item-row halves of the same batch col
    acc += __shfl_down(acc, 32);
    if (lane < 32) unsafeAtomicAdd(&sumexp[brow], acc);
}

// ---------------- final loss reduce ----------------
__global__ __launch_bounds__(256) void k_loss(const float* __restrict__ sumexp, const float* __restrict__ slabel,
                                              float* __restrict__ out) {
    __shared__ float ws[4];
    int t = threadIdx.x;
    float v = 0.f;
    for (int i = t; i < BATCH; i += 256)
        v += __logf(sumexp[i] - 96.0f) - slabel[i];   // -96: padded items contribute exp2(0)=1 each
#pragma unroll
    for (int off = 32; off > 0; off >>= 1) v += __shfl_down(v, off);
    if ((t & 63) == 0) ws[t >> 6] = v;
    __syncthreads();
    if (t == 0) out[0] = (ws[0] + ws[1] + ws[2] + ws[3]) * (1.f / (float)BATCH);
}

extern "C" void kernel_launch(void* const* d_in, const int* in_sizes, int n_in,
                              void* d_out, int out_size, void* d_ws, size_t ws_size,
                              hipStream_t stream) {
    const int*   user_seqs = (const int*)d_in[0];
    const int*   his       = (const int*)d_in[1];
    const int*   next_itm  = (const int*)d_in[2];
    const int*   adj_row   = (const int*)d_in[3];
    const int*   adj_col   = (const int*)d_in[4];
    const float* user_emb  = (const float*)d_in[6];
    const float* item_emb  = (const float*)d_in[7];
    float* out = (float*)d_out;
    int nedges = in_sizes[3];   // 12,800,000

    // Workspace layout (~183 MB). gcursor padded to 512 ints so every downstream
    // buffer stays 256B-aligned.
    unsigned char* w0 = (unsigned char*)d_ws;              // 12.8 MB each
    unsigned char* w1 = w0 + (size_t)N_NODES * D;
    unsigned char* w2 = w1 + (size_t)N_NODES * D;
    unsigned char* w3 = w2 + (size_t)N_NODES * D;
    float*  slabel = (float*)(w3 + (size_t)N_NODES * D);   // 2,048
    float*  sumexp = slabel + BATCH;                       // 2,048   (zeroed)
    int*    gcursor= (int*)(sumexp + BATCH);               // 512 (zeroed; 391 used)
    int*    rowptr = gcursor + 512;                        // 200,000
    int*    deg    = rowptr + N_NODES;                     // 200,000
    int*    staged = deg + N_NODES;                        // 391*36864 ints (57.7 MB)
    int*    ecols  = staged + (size_t)N_BUCKETS_RAW * BCAP; // 391*36864 ints (57.7 MB)
    ushort* item_bf = (ushort*)(ecols + (size_t)N_BUCKETS_RAW * BCAP);  // 100096*64 ushort, 256B-aligned
    ushort* pred_bf = item_bf + (size_t)N_ITEMS_PAD * D;   // 131072 ushort

    // zero sumexp + gcursor in one shot (contiguous)
    hipError_t _e = hipMemsetAsync(sumexp, 0, (size_t)(BATCH + 512) * sizeof(int), stream);
    (void)_e;

    int nchunks = (nedges + CHUNK - 1) / CHUNK;
    k_binA<<<nchunks, 256, 0, stream>>>(adj_row, adj_col, gcursor, staged, nedges);
    k_binB<<<N_BUCKETS_RAW, 512, 0, stream>>>(gcursor, staged, ecols, rowptr, deg,
                                              user_emb, item_emb, w0);

    k_prop<<<N_NODES / 32, 256, 0, stream>>>(rowptr, deg, ecols, w0, w1);
    k_prop<<<N_NODES / 32, 256, 0, stream>>>(rowptr, deg, ecols, w1, w2);
    k_prop<<<N_NODES / 32, 256, 0, stream>>>(rowptr, deg, ecols, w2, w3);

    k_conv_items<<<(N_ITEMS_PAD * (D / 4) + 255) / 256, 256, 0, stream>>>(item_emb, deg, w1, w2, w3, item_bf);
    k_pred<<<BATCH / 4, 256, 0, stream>>>(user_seqs, his, next_itm, user_emb, item_emb, deg,
                                          w1, w2, w3, pred_bf, slabel);

    dim3 gs(ISPLITS, BATCH / 128);
    k_scores<<<gs, 256, 0, stream>>>(item_bf, pred_bf, sumexp);

    k_loss<<<1, 256, 0, stream>>>(sumexp, slabel, out);
}

// Round 10
// 594.193 us; speedup vs baseline: 1.9706x; 1.0633x over previous
//
#include <hip/hip_runtime.h>
#include <hip/hip_bf16.h>
#include <cstddef>

// Problem constants (fixed by reference)
#define N_USERS   100000
#define N_ITEMS   100000
#define N_NODES   200000
#define D         64
#define BATCH     2048
#define HIST      50
#define N_ITEMS_PAD 100096   // padded to multiple of 128 (block item-chunk)

#define BUCKET_SHIFT 10                      // 1024 rows per bucket (R10: was 9)
#define BROWS (1 << BUCKET_SHIFT)
#define N_BUCKETS_RAW ((N_NODES + BROWS - 1) >> BUCKET_SHIFT)  // 196
#define CHUNK 8192                           // edges per binning block
#define EPT   (CHUNK / 256)                  // 32 edges per thread (8 x int4)
// Fixed bucket capacity: counts ~ Binomial(12.8M, 1024/200K): mean 65536, sigma 255.
// 73728 = mean + 32 sigma. Deterministic seed-0 dataset; guarded per-edge anyway.
#define BCAP 73728

// k_scores geometry: batch-stationary waves, item-streaming.
#define ISPLITS 92                           // 100096/32 = 3128 tiles = 92 * 34
#define TPS (N_ITEMS_PAD / 32 / ISPLITS)     // 34 item-tiles per x-block
#define LOG2E 1.44269504088896f

typedef __attribute__((ext_vector_type(8))) short short8;
typedef __attribute__((ext_vector_type(16))) float float16;
typedef __attribute__((ext_vector_type(2)))  float floatx2;

__device__ __forceinline__ float exp2fast(float x) {   // v_exp_f32 = 2^x
    return __builtin_amdgcn_exp2f(x);
}
__device__ __forceinline__ ushort f2bf(float x) {  // fp32 -> bf16 RNE
    unsigned u = __float_as_uint(x);
    return (ushort)((u + 0x7FFF + ((u >> 16) & 1)) >> 16);
}
__device__ __forceinline__ unsigned char f2fp8(float x) {  // fp32 -> fp8 e4m3 (OCP), RNE+sat
    int p = __builtin_amdgcn_cvt_pk_fp8_f32(x, x, 0, false);
    return (unsigned char)(p & 0xFF);
}
__device__ __forceinline__ float fp82f(unsigned char u) {  // fp8 e4m3 -> fp32
    return __builtin_amdgcn_cvt_f32_fp8((int)u, 0);
}

// ---------------- pass A: bin edges into fixed-capacity bucket arenas ----------------
// ONE return-LDS-atomic per edge: claim slot in LDS cursor, stash (slot<<18)|row in
// registers, reserve the block's bucket runs after a barrier, then place records
// (adj_col int4-reloaded, L2-warm). NO global atomics per edge (R2/R4 lesson).
// R10: 1024-row buckets -> runs ~42 edges (168B) halve the partial-line write
// amplification (117MB -> ~78MB) and halve gcursor reservation contention.
__global__ __launch_bounds__(256) void k_binA(const int* __restrict__ adj_row,
                                              const int* __restrict__ adj_col,
                                              int* __restrict__ gcursor, int* __restrict__ staged,
                                              int nedges) {
    __shared__ int cur[N_BUCKETS_RAW];
    __shared__ int lbase[N_BUCKETS_RAW];
    int t = threadIdx.x;
    int base = blockIdx.x * CHUNK;
    for (int i = t; i < N_BUCKETS_RAW; i += 256) cur[i] = 0;
    __syncthreads();
    int stash[EPT];
#pragma unroll
    for (int k = 0; k < EPT / 4; ++k) {
        int e0 = base + (k * 256 + t) * 4;
        if (e0 + 3 < nedges) {
            int4 r4 = *(const int4*)(adj_row + e0);
            int p;
            p = atomicAdd(&cur[r4.x >> BUCKET_SHIFT], 1); stash[4 * k    ] = (p << 18) | r4.x;
            p = atomicAdd(&cur[r4.y >> BUCKET_SHIFT], 1); stash[4 * k + 1] = (p << 18) | r4.y;
            p = atomicAdd(&cur[r4.z >> BUCKET_SHIFT], 1); stash[4 * k + 2] = (p << 18) | r4.z;
            p = atomicAdd(&cur[r4.w >> BUCKET_SHIFT], 1); stash[4 * k + 3] = (p << 18) | r4.w;
        } else {
#pragma unroll
            for (int j = 0; j < 4; ++j) {
                int e = e0 + j;
                if (e < nedges) {
                    int r = adj_row[e];
                    int p = atomicAdd(&cur[r >> BUCKET_SHIFT], 1);
                    stash[4 * k + j] = (p << 18) | r;
                } else stash[4 * k + j] = -1;
            }
        }
    }
    __syncthreads();
    for (int b = t; b < N_BUCKETS_RAW; b += 256) {
        int c = cur[b];
        int s = (c > 0) ? atomicAdd(&gcursor[b], c) : 0;
        lbase[b] = b * BCAP + s;
    }
    __syncthreads();
#pragma unroll
    for (int k = 0; k < EPT / 4; ++k) {
        int e0 = base + (k * 256 + t) * 4;
        if (e0 + 3 < nedges) {
            int4 c4 = *(const int4*)(adj_col + e0);
#pragma unroll
            for (int j = 0; j < 4; ++j) {
                int v = stash[4 * k + j];
                int c = (j == 0) ? c4.x : (j == 1) ? c4.y : (j == 2) ? c4.z : c4.w;
                int r = v & 0x3FFFF;
                int b = r >> BUCKET_SHIFT;
                int pos = lbase[b] + (v >> 18);
                if (pos < (b + 1) * BCAP)             // overflow guard (never fires)
                    staged[pos] = ((r & (BROWS - 1)) << 18) | c;
            }
        } else {
#pragma unroll
            for (int j = 0; j < 4; ++j) {
                int v = stash[4 * k + j];
                if (v >= 0) {
                    int e = e0 + j;
                    int c = adj_col[e];
                    int r = v & 0x3FFFF;
                    int b = r >> BUCKET_SHIFT;
                    int pos = lbase[b] + (v >> 18);
                    if (pos < (b + 1) * BCAP)
                        staged[pos] = ((r & (BROWS - 1)) << 18) | c;
                }
            }
        }
    }
}

// ---------------- pass B: per bucket (1024 rows, 1024 threads), LDS count+scan ->
// packed ecols/rowptr/deg; fused w0-init ----------------
__global__ __launch_bounds__(1024) void k_binB(const int* __restrict__ gcursor, const int* __restrict__ staged,
                                               int* __restrict__ ecols, int* __restrict__ rowptr,
                                               int* __restrict__ deg,
                                               const float* __restrict__ user_emb,
                                               const float* __restrict__ item_emb,
                                               unsigned char* __restrict__ w0) {
    __shared__ int cnt[BROWS];
    __shared__ int scn[BROWS];
    __shared__ int cur[BROWS];
    int b = blockIdx.x, t = threadIdx.x;
    cnt[t] = 0;
    __syncthreads();
    int nb = gcursor[b]; if (nb > BCAP) nb = BCAP;
    size_t es = (size_t)b * BCAP;
    for (int e = t; e < nb; e += 1024) atomicAdd(&cnt[staged[es + e] >> 18], 1);
    __syncthreads();
    int myc = cnt[t];
    scn[t] = myc;
    __syncthreads();
    for (int off = 1; off < BROWS; off <<= 1) {
        int v = (t >= off) ? scn[t - off] : 0;
        __syncthreads();
        scn[t] += v;
        __syncthreads();
    }
    int excl = scn[t] - myc;
    int r = (b << BUCKET_SHIFT) + t;
    int gpos = b * BCAP + excl;
    if (r < N_NODES) { rowptr[r] = gpos; deg[r] = myc; }
    cur[t] = gpos;
    __syncthreads();
    for (int e = t; e < nb; e += 1024) {
        int v = staged[es + e];
        int pos = atomicAdd(&cur[v >> 18], 1);
        ecols[pos] = (v & 0x3FFFF) << 6;   // byte offset into fp8 node rows
    }
    // fused init for this bucket's rows (cnt[] is stable; cur/scn unused here)
    int r0 = b << BUCKET_SHIFT;
    for (int f = t; f < BROWS * 16; f += 1024) {
        int lr = f >> 4;
        int row = r0 + lr;
        if (row >= N_NODES) continue;
        const float4* src = (row < N_USERS)
            ? ((const float4*)user_emb) + (size_t)row * 16 + (f & 15)
            : ((const float4*)item_emb) + (size_t)(row - (N_USERS - 1)) * 16 + (f & 15);
        float4 v = *src;
        int dg = cnt[lr]; if (dg < 1) dg = 1;
        float sc = 64.f * __frsqrt_rn((float)dg);
        uchar4 o;
        o.x = f2fp8(v.x * sc); o.y = f2fp8(v.y * sc);
        o.z = f2fp8(v.z * sc); o.w = f2fp8(v.w * sc);
        ((uchar4*)w0)[(size_t)row * 16 + (f & 15)] = o;
    }
}

// ---------------- propagate (fp8 z-space): w_out[r] = (1/deg_r) * sum w_in[c] ----------------
// v4: group-per-row (8 rows x 8 dim-lanes, no cross-lane reduce) + 8-deep gather
// pipeline. MLP arithmetic: 12.8M 64B gathers at ~300cy L2/L3 latency needs ~180
// outstanding/CU; bulk-4 x ~24 waves gave ~100 -> bulk-8 doubles it.
#define ACC8(v)                                               \
    a01 += __builtin_amdgcn_cvt_pk_f32_fp8((int)(v).x, false); \
    a23 += __builtin_amdgcn_cvt_pk_f32_fp8((int)(v).x, true);  \
    a45 += __builtin_amdgcn_cvt_pk_f32_fp8((int)(v).y, false); \
    a67 += __builtin_amdgcn_cvt_pk_f32_fp8((int)(v).y, true);

__global__ __launch_bounds__(256) void k_prop(const int* __restrict__ rowptr, const int* __restrict__ deg,
                                              const int* __restrict__ ecols,
                                              const unsigned char* __restrict__ x_in,
                                              unsigned char* __restrict__ x_out) {
    int lane = threadIdx.x & 63;
    int row = blockIdx.x * 32 + (threadIdx.x >> 6) * 8 + (lane >> 3);
    int d8 = (lane & 7) * 8;       // 8 dims per lane
    int s = rowptr[row];
    int cnt = deg[row];
    const int* ec = ecols + s;
    const unsigned char* xb = x_in + d8;
    // wave-wide min/max of cnt across the 8 row-groups
    int cmin = cnt, cmax = cnt;
#pragma unroll
    for (int off = 8; off < 64; off <<= 1) {
        cmin = min(cmin, __shfl_xor(cmin, off));
        cmax = max(cmax, __shfl_xor(cmax, off));
    }
    floatx2 a01 = {0.f, 0.f}, a23 = {0.f, 0.f}, a45 = {0.f, 0.f}, a67 = {0.f, 0.f};
    int e = 0;
    for (; e + 8 <= cmin; e += 8) {  // unguarded bulk: 8 gathers in flight
        int c0 = ec[e];
        int c1 = ec[e + 1];
        int c2 = ec[e + 2];
        int c3 = ec[e + 3];
        int c4 = ec[e + 4];
        int c5 = ec[e + 5];
        int c6 = ec[e + 6];
        int c7 = ec[e + 7];
        uint2 v0 = *(const uint2*)(xb + c0);
        uint2 v1 = *(const uint2*)(xb + c1);
        uint2 v2 = *(const uint2*)(xb + c2);
        uint2 v3 = *(const uint2*)(xb + c3);
        uint2 v4 = *(const uint2*)(xb + c4);
        uint2 v5 = *(const uint2*)(xb + c5);
        uint2 v6 = *(const uint2*)(xb + c6);
        uint2 v7 = *(const uint2*)(xb + c7);
        ACC8(v0) ACC8(v1) ACC8(v2) ACC8(v3)
        ACC8(v4) ACC8(v5) ACC8(v6) ACC8(v7)
    }
    for (; e + 4 <= cmin; e += 4) {  // 4-deep remainder toward cmin
        int c0 = ec[e];
        int c1 = ec[e + 1];
        int c2 = ec[e + 2];
        int c3 = ec[e + 3];
        uint2 v0 = *(const uint2*)(xb + c0);
        uint2 v1 = *(const uint2*)(xb + c1);
        uint2 v2 = *(const uint2*)(xb + c2);
        uint2 v3 = *(const uint2*)(xb + c3);
        ACC8(v0) ACC8(v1) ACC8(v2) ACC8(v3)
    }
    for (; e < cmax; e += 2) {       // clamp+cndmask tail (group-uniform predicates)
        bool k0 = e < cnt, k1 = e + 1 < cnt;
        int c0 = ec[k0 ? e : 0];
        int c1 = ec[k1 ? e + 1 : 0];
        uint2 v0 = *(const uint2*)(xb + c0);
        uint2 v1 = *(const uint2*)(xb + c1);
        v0.x = k0 ? v0.x : 0u; v0.y = k0 ? v0.y : 0u;
        v1.x = k1 ? v1.x : 0u; v1.y = k1 ? v1.y : 0u;
        ACC8(v0) ACC8(v1)
    }
    float inv = (cnt > 0) ? 1.f / (float)cnt : 0.f;
    int w01 = __builtin_amdgcn_cvt_pk_fp8_f32(a01.x * inv, a01.y * inv, 0, false);
    w01     = __builtin_amdgcn_cvt_pk_fp8_f32(a23.x * inv, a23.y * inv, w01, true);
    int w23 = __builtin_amdgcn_cvt_pk_fp8_f32(a45.x * inv, a45.y * inv, 0, false);
    w23     = __builtin_amdgcn_cvt_pk_fp8_f32(a67.x * inv, a67.y * inv, w23, true);
    uint2 o; o.x = (unsigned)w01; o.y = (unsigned)w23;
    *(uint2*)(x_out + (size_t)row * D + d8) = o;   // 64B/row, contiguous per wave
}

// ---------------- item latents, fragment-tiled + log2e-scaled ----------------
__global__ void k_conv_items(const float* __restrict__ item_emb, const int* __restrict__ deg,
                             const unsigned char* __restrict__ w1, const unsigned char* __restrict__ w2,
                             const unsigned char* __restrict__ w3, ushort* __restrict__ item_bf) {
    int f = blockIdx.x * 256 + threadIdx.x;    // one 4-dim group
    if (f >= N_ITEMS_PAD * (D / 4)) return;
    int row = f >> 4, c4 = f & 15;
    ushort4 o;
    if (row < N_ITEMS) {
        int node = N_USERS + row;
        int dg = deg[node]; if (dg < 1) dg = 1;
        float s = sqrtf((float)dg) * (1.f / 256.f);    // sqrt(deg)/(64 scale * 4 avg)
        float4 e4 = ((const float4*)(item_emb + (size_t)(row + 1) * D))[c4];
        size_t n4 = (size_t)node * 16 + c4;
        uchar4 a = ((const uchar4*)w1)[n4];
        uchar4 b = ((const uchar4*)w2)[n4];
        uchar4 c = ((const uchar4*)w3)[n4];
        o.x = f2bf(LOG2E * (0.25f * e4.x + s * (fp82f(a.x) + fp82f(b.x) + fp82f(c.x))));
        o.y = f2bf(LOG2E * (0.25f * e4.y + s * (fp82f(a.y) + fp82f(b.y) + fp82f(c.y))));
        o.z = f2bf(LOG2E * (0.25f * e4.z + s * (fp82f(a.z) + fp82f(b.z) + fp82f(c.z))));
        o.w = f2bf(LOG2E * (0.25f * e4.w + s * (fp82f(a.w) + fp82f(b.w) + fp82f(c.w))));
    } else {
        o.x = o.y = o.z = o.w = 0;   // pad rows -> score 0 -> exp2 = 1 (subtract 96 in k_loss)
    }
    int tile = row >> 5, rr = row & 31;
    int q = c4 >> 2, half = (c4 >> 1) & 1, e0 = (c4 & 1) * 4;
    size_t idx = (size_t)tile * 2048 + q * 512 + (rr + 32 * half) * 8 + e0;
    *(ushort4*)(item_bf + idx) = o;
}

// ---------------- pred (bf16 copy) + label score ----------------
__global__ __launch_bounds__(256) void k_pred(const int* __restrict__ user_seqs, const int* __restrict__ his,
                                              const int* __restrict__ next_items,
                                              const float* __restrict__ user_emb, const float* __restrict__ item_emb,
                                              const int* __restrict__ deg,
                                              const unsigned char* __restrict__ w1, const unsigned char* __restrict__ w2,
                                              const unsigned char* __restrict__ w3,
                                              ushort* __restrict__ pred_bf, float* __restrict__ slabel) {
    int b = blockIdx.x * 4 + (threadIdx.x >> 6);
    int lane = threadIdx.x & 63;
    int u = user_seqs[b];
    float hsum = 0.f; int cnt = 0;
    for (int j = 0; j < HIST; ++j) {
        int it = his[b * HIST + j];
        cnt += (it != 0);
        hsum += item_emb[(size_t)it * D + lane];   // item_emb[0] is all-zero (pad)
    }
    int du = deg[u]; if (du < 1) du = 1;
    float su = sqrtf((float)du) * (1.f / 256.f);
    size_t ur = (size_t)u * D + lane;
    float ulat = 0.25f * user_emb[ur] + su * (fp82f(w1[ur]) + fp82f(w2[ur]) + fp82f(w3[ur]));
    float pv = ulat + hsum / (float)cnt;
    pred_bf[(size_t)b * D + lane] = f2bf(pv);
    int lab = next_items[b] - 1;
    int node = N_USERS + lab;
    int di = deg[node]; if (di < 1) di = 1;
    float si = sqrtf((float)di) * (1.f / 256.f);
    size_t nr = (size_t)node * D + lane;
    float ilat = 0.25f * item_emb[(size_t)(lab + 1) * D + lane]
               + si * (fp82f(w1[nr]) + fp82f(w2[nr]) + fp82f(w3[nr]));
    float tv = pv * ilat;
#pragma unroll
    for (int off = 32; off > 0; off >>= 1) tv += __shfl_down(tv, off);
    if (lane == 0) slabel[b] = tv;
}

// ---------------- MFMA scores + max-free sumexp (batch-stationary, frag-tiled items) ----------------
#define MFMA __builtin_amdgcn_mfma_f32_32x32x16_bf16
__global__ __launch_bounds__(256) void k_scores(const ushort* __restrict__ item_bf,
                                                const ushort* __restrict__ pred_bf,
                                                float* __restrict__ sumexp) {
    int t = threadIdx.x, wv = t >> 6, lane = t & 63;
    int l31 = lane & 31;
    int khalf = (lane >> 5) * 8;   // which 8-elem k-half this lane holds

    int brow = blockIdx.y * 128 + wv * 32 + l31;        // this lane's batch column
    const ushort* pb = pred_bf + (size_t)brow * D + khalf;
    short8 b0 = *(const short8*)(pb);
    short8 b1 = *(const short8*)(pb + 16);
    short8 b2 = *(const short8*)(pb + 32);
    short8 b3 = *(const short8*)(pb + 48);

    const ushort* ib = item_bf + (size_t)blockIdx.x * TPS * 2048 + lane * 8;
    float acc = 0.f;

    short8 x0 = *(const short8*)(ib);
    short8 x1 = *(const short8*)(ib + 512);
    short8 x2 = *(const short8*)(ib + 1024);
    short8 x3 = *(const short8*)(ib + 1536);
    short8 x4 = *(const short8*)(ib + 2048);
    short8 x5 = *(const short8*)(ib + 2560);
    short8 x6 = *(const short8*)(ib + 3072);
    short8 x7 = *(const short8*)(ib + 3584);

    for (int tt = 0; tt < TPS; tt += 2) {
        // prefetch next pair (last iteration reads 8KB past this split's tiles —
        // lands in the next split / pred_bf region, valid memory, never used)
        const ushort* in = ib + (size_t)(tt + 2) * 2048;
        short8 y0 = *(const short8*)(in);
        short8 y1 = *(const short8*)(in + 512);
        short8 y2 = *(const short8*)(in + 1024);
        short8 y3 = *(const short8*)(in + 1536);
        short8 y4 = *(const short8*)(in + 2048);
        short8 y5 = *(const short8*)(in + 2560);
        short8 y6 = *(const short8*)(in + 3072);
        short8 y7 = *(const short8*)(in + 3584);
        float16 c0 = {0.f};
        float16 c1 = {0.f};
        c0 = MFMA(x0, b0, c0, 0, 0, 0);
        c1 = MFMA(x4, b0, c1, 0, 0, 0);
        c0 = MFMA(x1, b1, c0, 0, 0, 0);
        c1 = MFMA(x5, b1, c1, 0, 0, 0);
        c0 = MFMA(x2, b2, c0, 0, 0, 0);
        c1 = MFMA(x6, b2, c1, 0, 0, 0);
        c0 = MFMA(x3, b3, c0, 0, 0, 0);
        c1 = MFMA(x7, b3, c1, 0, 0, 0);
        float s0 = 0.f, s1 = 0.f, s2 = 0.f, s3 = 0.f;
#pragma unroll
        for (int r = 0; r < 16; r += 4) {
            s0 += exp2fast(c0[r]);
            s1 += exp2fast(c0[r + 1]);
            s2 += exp2fast(c0[r + 2]);
            s3 += exp2fast(c0[r + 3]);
        }
#pragma unroll
        for (int r = 0; r < 16; r += 4) {
            s0 += exp2fast(c1[r]);
            s1 += exp2fast(c1[r + 1]);
            s2 += exp2fast(c1[r + 2]);
            s3 += exp2fast(c1[r + 3]);
        }
        acc += (s0 + s1) + (s2 + s3);
        x0 = y0; x1 = y1; x2 = y2; x3 = y3;
        x4 = y4; x5 = y5; x6 = y6; x7 = y7;
    }
    // lane L and L+32 hold the two item-row halves of the same batch col
    acc += __shfl_down(acc, 32);
    if (lane < 32) unsafeAtomicAdd(&sumexp[brow], acc);
}

// ---------------- final loss reduce ----------------
__global__ __launch_bounds__(256) void k_loss(const float* __restrict__ sumexp, const float* __restrict__ slabel,
                                              float* __restrict__ out) {
    __shared__ float ws[4];
    int t = threadIdx.x;
    float v = 0.f;
    for (int i = t; i < BATCH; i += 256)
        v += __logf(sumexp[i] - 96.0f) - slabel[i];   // -96: padded items contribute exp2(0)=1 each
#pragma unroll
    for (int off = 32; off > 0; off >>= 1) v += __shfl_down(v, off);
    if ((t & 63) == 0) ws[t >> 6] = v;
    __syncthreads();
    if (t == 0) out[0] = (ws[0] + ws[1] + ws[2] + ws[3]) * (1.f / (float)BATCH);
}

extern "C" void kernel_launch(void* const* d_in, const int* in_sizes, int n_in,
                              void* d_out, int out_size, void* d_ws, size_t ws_size,
                              hipStream_t stream) {
    const int*   user_seqs = (const int*)d_in[0];
    const int*   his       = (const int*)d_in[1];
    const int*   next_itm  = (const int*)d_in[2];
    const int*   adj_row   = (const int*)d_in[3];
    const int*   adj_col   = (const int*)d_in[4];
    const float* user_emb  = (const float*)d_in[6];
    const float* item_emb  = (const float*)d_in[7];
    float* out = (float*)d_out;
    int nedges = in_sizes[3];   // 12,800,000

    // Workspace layout (~183 MB). gcursor padded to 512 ints so every downstream
    // buffer stays 256B-aligned.
    unsigned char* w0 = (unsigned char*)d_ws;              // 12.8 MB each
    unsigned char* w1 = w0 + (size_t)N_NODES * D;
    unsigned char* w2 = w1 + (size_t)N_NODES * D;
    unsigned char* w3 = w2 + (size_t)N_NODES * D;
    float*  slabel = (float*)(w3 + (size_t)N_NODES * D);   // 2,048
    float*  sumexp = slabel + BATCH;                       // 2,048   (zeroed)
    int*    gcursor= (int*)(sumexp + BATCH);               // 512 (zeroed; 196 used)
    int*    rowptr = gcursor + 512;                        // 200,000
    int*    deg    = rowptr + N_NODES;                     // 200,000
    int*    staged = deg + N_NODES;                        // 196*73728 ints (57.8 MB)
    int*    ecols  = staged + (size_t)N_BUCKETS_RAW * BCAP; // 196*73728 ints (57.8 MB)
    ushort* item_bf = (ushort*)(ecols + (size_t)N_BUCKETS_RAW * BCAP);  // 100096*64 ushort, 256B-aligned
    ushort* pred_bf = item_bf + (size_t)N_ITEMS_PAD * D;   // 131072 ushort

    // zero sumexp + gcursor in one shot (contiguous)
    hipError_t _e = hipMemsetAsync(sumexp, 0, (size_t)(BATCH + 512) * sizeof(int), stream);
    (void)_e;

    int nchunks = (nedges + CHUNK - 1) / CHUNK;
    k_binA<<<nchunks, 256, 0, stream>>>(adj_row, adj_col, gcursor, staged, nedges);
    k_binB<<<N_BUCKETS_RAW, 1024, 0, stream>>>(gcursor, staged, ecols, rowptr, deg,
                                               user_emb, item_emb, w0);

    k_prop<<<N_NODES / 32, 256, 0, stream>>>(rowptr, deg, ecols, w0, w1);
    k_prop<<<N_NODES / 32, 256, 0, stream>>>(rowptr, deg, ecols, w1, w2);
    k_prop<<<N_NODES / 32, 256, 0, stream>>>(rowptr, deg, ecols, w2, w3);

    k_conv_items<<<(N_ITEMS_PAD * (D / 4) + 255) / 256, 256, 0, stream>>>(item_emb, deg, w1, w2, w3, item_bf);
    k_pred<<<BATCH / 4, 256, 0, stream>>>(user_seqs, his, next_itm, user_emb, item_emb, deg,
                                          w1, w2, w3, pred_bf, slabel);

    dim3 gs(ISPLITS, BATCH / 128);
    k_scores<<<gs, 256, 0, stream>>>(item_bf, pred_bf, sumexp);

    k_loss<<<1, 256, 0, stream>>>(sumexp, slabel, out);
}

// Round 11
// 566.557 us; speedup vs baseline: 2.0668x; 1.0488x over previous
//
#include <hip/hip_runtime.h>
#include <hip/hip_bf16.h>
#include <cstddef>

// Problem constants (fixed by reference)
#define N_USERS   100000
#define N_ITEMS   100000
#define N_NODES   200000
#define D         64
#define BATCH     2048
#define HIST      50
#define N_ITEMS_PAD 100096   // padded to multiple of 128 (block item-chunk)

#define BUCKET_SHIFT 10                      // 1024 rows per bucket
#define BROWS (1 << BUCKET_SHIFT)
#define N_BUCKETS_RAW ((N_NODES + BROWS - 1) >> BUCKET_SHIFT)  // 196
#define CHUNK 8192                           // edges per binning block
#define EPT   (CHUNK / 256)                  // 32 edges per thread (8 x int4)
// Fixed bucket capacity: counts ~ Binomial(12.8M, 1024/200K): mean 65536, sigma 255.
// 73728 = mean + 32 sigma. Deterministic seed-0 dataset; guarded per-edge anyway.
#define BCAP 73728
// Half-bucket LDS output buffer: Binomial(12.8M, 512/200K) mean 32768 sigma 181;
// 36864 = +22 sigma. 144 KB of LDS.
#define HBUF 36864

// k_scores geometry: batch-stationary waves, item-streaming.
#define ISPLITS 92                           // 100096/32 = 3128 tiles = 92 * 34
#define TPS (N_ITEMS_PAD / 32 / ISPLITS)     // 34 item-tiles per x-block
#define LOG2E 1.44269504088896f

typedef __attribute__((ext_vector_type(8))) short short8;
typedef __attribute__((ext_vector_type(16))) float float16;
typedef __attribute__((ext_vector_type(2)))  float floatx2;

__device__ __forceinline__ float exp2fast(float x) {   // v_exp_f32 = 2^x
    return __builtin_amdgcn_exp2f(x);
}
__device__ __forceinline__ ushort f2bf(float x) {  // fp32 -> bf16 RNE
    unsigned u = __float_as_uint(x);
    return (ushort)((u + 0x7FFF + ((u >> 16) & 1)) >> 16);
}
__device__ __forceinline__ unsigned char f2fp8(float x) {  // fp32 -> fp8 e4m3 (OCP), RNE+sat
    int p = __builtin_amdgcn_cvt_pk_fp8_f32(x, x, 0, false);
    return (unsigned char)(p & 0xFF);
}
__device__ __forceinline__ float fp82f(unsigned char u) {  // fp8 e4m3 -> fp32
    return __builtin_amdgcn_cvt_f32_fp8((int)u, 0);
}

// ---------------- pass A: bin edges into fixed-capacity bucket arenas ----------------
// ONE return-LDS-atomic per edge: claim slot in LDS cursor, stash (slot<<18)|row in
// registers, reserve the block's bucket runs after a barrier, then place records
// (adj_col int4-reloaded, L2-warm). NO global atomics per edge (R2/R4 lesson).
__global__ __launch_bounds__(256) void k_binA(const int* __restrict__ adj_row,
                                              const int* __restrict__ adj_col,
                                              int* __restrict__ gcursor, int* __restrict__ staged,
                                              int nedges) {
    __shared__ int cur[N_BUCKETS_RAW];
    __shared__ int lbase[N_BUCKETS_RAW];
    int t = threadIdx.x;
    int base = blockIdx.x * CHUNK;
    for (int i = t; i < N_BUCKETS_RAW; i += 256) cur[i] = 0;
    __syncthreads();
    int stash[EPT];
#pragma unroll
    for (int k = 0; k < EPT / 4; ++k) {
        int e0 = base + (k * 256 + t) * 4;
        if (e0 + 3 < nedges) {
            int4 r4 = *(const int4*)(adj_row + e0);
            int p;
            p = atomicAdd(&cur[r4.x >> BUCKET_SHIFT], 1); stash[4 * k    ] = (p << 18) | r4.x;
            p = atomicAdd(&cur[r4.y >> BUCKET_SHIFT], 1); stash[4 * k + 1] = (p << 18) | r4.y;
            p = atomicAdd(&cur[r4.z >> BUCKET_SHIFT], 1); stash[4 * k + 2] = (p << 18) | r4.z;
            p = atomicAdd(&cur[r4.w >> BUCKET_SHIFT], 1); stash[4 * k + 3] = (p << 18) | r4.w;
        } else {
#pragma unroll
            for (int j = 0; j < 4; ++j) {
                int e = e0 + j;
                if (e < nedges) {
                    int r = adj_row[e];
                    int p = atomicAdd(&cur[r >> BUCKET_SHIFT], 1);
                    stash[4 * k + j] = (p << 18) | r;
                } else stash[4 * k + j] = -1;
            }
        }
    }
    __syncthreads();
    for (int b = t; b < N_BUCKETS_RAW; b += 256) {
        int c = cur[b];
        int s = (c > 0) ? atomicAdd(&gcursor[b], c) : 0;
        lbase[b] = b * BCAP + s;
    }
    __syncthreads();
#pragma unroll
    for (int k = 0; k < EPT / 4; ++k) {
        int e0 = base + (k * 256 + t) * 4;
        if (e0 + 3 < nedges) {
            int4 c4 = *(const int4*)(adj_col + e0);
#pragma unroll
            for (int j = 0; j < 4; ++j) {
                int v = stash[4 * k + j];
                int c = (j == 0) ? c4.x : (j == 1) ? c4.y : (j == 2) ? c4.z : c4.w;
                int r = v & 0x3FFFF;
                int b = r >> BUCKET_SHIFT;
                int pos = lbase[b] + (v >> 18);
                if (pos < (b + 1) * BCAP)             // overflow guard (never fires)
                    staged[pos] = ((r & (BROWS - 1)) << 18) | c;
            }
        } else {
#pragma unroll
            for (int j = 0; j < 4; ++j) {
                int v = stash[4 * k + j];
                if (v >= 0) {
                    int e = e0 + j;
                    int c = adj_col[e];
                    int r = v & 0x3FFFF;
                    int b = r >> BUCKET_SHIFT;
                    int pos = lbase[b] + (v >> 18);
                    if (pos < (b + 1) * BCAP)
                        staged[pos] = ((r & (BROWS - 1)) << 18) | c;
                }
            }
        }
    }
}

// ---------------- pass B v3: LDS-staged packed output (kills 3x write amp) ----------------
// Per bucket (1024 rows): count -> scan -> for each 512-row half, place the half's
// edges into an LDS buffer (random LDS writes are free of line granularity), then
// stream the packed 128KB run to ecols CONTIGUOUSLY. staged re-reads in the half
// passes hit L2 (256KB window). WRITE_SIZE: 200MB -> ~66MB. Fused w0-init kept.
__global__ __launch_bounds__(1024) void k_binB(const int* __restrict__ gcursor, const int* __restrict__ staged,
                                               int* __restrict__ ecols, int* __restrict__ rowptr,
                                               int* __restrict__ deg,
                                               const float* __restrict__ user_emb,
                                               const float* __restrict__ item_emb,
                                               unsigned char* __restrict__ w0) {
    __shared__ int cnt[BROWS];        // 4 KB
    __shared__ int scn[BROWS];        // 4 KB
    __shared__ int cur[BROWS / 2];    // 2 KB
    __shared__ int lbuf[HBUF];        // 144 KB  (total 154 KB < 160 KB)
    int b = blockIdx.x, t = threadIdx.x;
    cnt[t] = 0;
    __syncthreads();
    int nb = gcursor[b]; if (nb > BCAP) nb = BCAP;
    size_t es = (size_t)b * BCAP;
    for (int e = t; e < nb; e += 1024) atomicAdd(&cnt[staged[es + e] >> 18], 1);
    __syncthreads();
    int myc = cnt[t];
    scn[t] = myc;
    __syncthreads();
    for (int off = 1; off < BROWS; off <<= 1) {
        int v = (t >= off) ? scn[t - off] : 0;
        __syncthreads();
        scn[t] += v;
        __syncthreads();
    }
    int r = (b << BUCKET_SHIFT) + t;
    if (r < N_NODES) { rowptr[r] = b * BCAP + scn[t] - myc; deg[r] = myc; }
    // two half-passes: place into LDS, then contiguous copy-out
    for (int h = 0; h < 2; ++h) {
        int hbase = h << 9;                            // 0 or 512
        int excl0 = (h == 0) ? 0 : scn[511];
        if (t < 512) cur[t] = scn[hbase + t] - cnt[hbase + t] - excl0;
        __syncthreads();
        for (int e = t; e < nb; e += 1024) {
            int v = staged[es + e];
            int rr = v >> 18;
            if ((rr >> 9) == h) {
                int lp = atomicAdd(&cur[rr & 511], 1);
                if (lp < HBUF)                          // overflow guard (never fires)
                    lbuf[lp] = (v & 0x3FFFF) << 6;      // byte offset into fp8 rows
            }
        }
        __syncthreads();
        int tot = ((h == 0) ? scn[511] : scn[BROWS - 1]) - excl0;
        if (tot > HBUF) tot = HBUF;
        int obase = b * BCAP + excl0;
        for (int i = t; i < tot; i += 1024) ecols[obase + i] = lbuf[i];
        __syncthreads();
    }
    // fused init for this bucket's rows (cnt[] is stable)
    int r0 = b << BUCKET_SHIFT;
    for (int f = t; f < BROWS * 16; f += 1024) {
        int lr = f >> 4;
        int row = r0 + lr;
        if (row >= N_NODES) continue;
        const float4* src = (row < N_USERS)
            ? ((const float4*)user_emb) + (size_t)row * 16 + (f & 15)
            : ((const float4*)item_emb) + (size_t)(row - (N_USERS - 1)) * 16 + (f & 15);
        float4 v = *src;
        int dg = cnt[lr]; if (dg < 1) dg = 1;
        float sc = 64.f * __frsqrt_rn((float)dg);
        uchar4 o;
        o.x = f2fp8(v.x * sc); o.y = f2fp8(v.y * sc);
        o.z = f2fp8(v.z * sc); o.w = f2fp8(v.w * sc);
        ((uchar4*)w0)[(size_t)row * 16 + (f & 15)] = o;
    }
}

// ---------------- propagate (fp8 z-space): w_out[r] = (1/deg_r) * sum w_in[c] ----------------
// v4: group-per-row (8 rows x 8 dim-lanes, no cross-lane reduce) + 8-deep gather pipeline.
#define ACC8(v)                                               \
    a01 += __builtin_amdgcn_cvt_pk_f32_fp8((int)(v).x, false); \
    a23 += __builtin_amdgcn_cvt_pk_f32_fp8((int)(v).x, true);  \
    a45 += __builtin_amdgcn_cvt_pk_f32_fp8((int)(v).y, false); \
    a67 += __builtin_amdgcn_cvt_pk_f32_fp8((int)(v).y, true);

__global__ __launch_bounds__(256) void k_prop(const int* __restrict__ rowptr, const int* __restrict__ deg,
                                              const int* __restrict__ ecols,
                                              const unsigned char* __restrict__ x_in,
                                              unsigned char* __restrict__ x_out) {
    int lane = threadIdx.x & 63;
    int row = blockIdx.x * 32 + (threadIdx.x >> 6) * 8 + (lane >> 3);
    int d8 = (lane & 7) * 8;       // 8 dims per lane
    int s = rowptr[row];
    int cnt = deg[row];
    const int* ec = ecols + s;
    const unsigned char* xb = x_in + d8;
    // wave-wide min/max of cnt across the 8 row-groups
    int cmin = cnt, cmax = cnt;
#pragma unroll
    for (int off = 8; off < 64; off <<= 1) {
        cmin = min(cmin, __shfl_xor(cmin, off));
        cmax = max(cmax, __shfl_xor(cmax, off));
    }
    floatx2 a01 = {0.f, 0.f}, a23 = {0.f, 0.f}, a45 = {0.f, 0.f}, a67 = {0.f, 0.f};
    int e = 0;
    for (; e + 8 <= cmin; e += 8) {  // unguarded bulk: 8 gathers in flight
        int c0 = ec[e];
        int c1 = ec[e + 1];
        int c2 = ec[e + 2];
        int c3 = ec[e + 3];
        int c4 = ec[e + 4];
        int c5 = ec[e + 5];
        int c6 = ec[e + 6];
        int c7 = ec[e + 7];
        uint2 v0 = *(const uint2*)(xb + c0);
        uint2 v1 = *(const uint2*)(xb + c1);
        uint2 v2 = *(const uint2*)(xb + c2);
        uint2 v3 = *(const uint2*)(xb + c3);
        uint2 v4 = *(const uint2*)(xb + c4);
        uint2 v5 = *(const uint2*)(xb + c5);
        uint2 v6 = *(const uint2*)(xb + c6);
        uint2 v7 = *(const uint2*)(xb + c7);
        ACC8(v0) ACC8(v1) ACC8(v2) ACC8(v3)
        ACC8(v4) ACC8(v5) ACC8(v6) ACC8(v7)
    }
    for (; e + 4 <= cmin; e += 4) {  // 4-deep remainder toward cmin
        int c0 = ec[e];
        int c1 = ec[e + 1];
        int c2 = ec[e + 2];
        int c3 = ec[e + 3];
        uint2 v0 = *(const uint2*)(xb + c0);
        uint2 v1 = *(const uint2*)(xb + c1);
        uint2 v2 = *(const uint2*)(xb + c2);
        uint2 v3 = *(const uint2*)(xb + c3);
        ACC8(v0) ACC8(v1) ACC8(v2) ACC8(v3)
    }
    for (; e < cmax; e += 2) {       // clamp+cndmask tail (group-uniform predicates)
        bool k0 = e < cnt, k1 = e + 1 < cnt;
        int c0 = ec[k0 ? e : 0];
        int c1 = ec[k1 ? e + 1 : 0];
        uint2 v0 = *(const uint2*)(xb + c0);
        uint2 v1 = *(const uint2*)(xb + c1);
        v0.x = k0 ? v0.x : 0u; v0.y = k0 ? v0.y : 0u;
        v1.x = k1 ? v1.x : 0u; v1.y = k1 ? v1.y : 0u;
        ACC8(v0) ACC8(v1)
    }
    float inv = (cnt > 0) ? 1.f / (float)cnt : 0.f;
    int w01 = __builtin_amdgcn_cvt_pk_fp8_f32(a01.x * inv, a01.y * inv, 0, false);
    w01     = __builtin_amdgcn_cvt_pk_fp8_f32(a23.x * inv, a23.y * inv, w01, true);
    int w23 = __builtin_amdgcn_cvt_pk_fp8_f32(a45.x * inv, a45.y * inv, 0, false);
    w23     = __builtin_amdgcn_cvt_pk_fp8_f32(a67.x * inv, a67.y * inv, w23, true);
    uint2 o; o.x = (unsigned)w01; o.y = (unsigned)w23;
    *(uint2*)(x_out + (size_t)row * D + d8) = o;   // 64B/row, contiguous per wave
}

// ---------------- item latents, fragment-tiled + log2e-scaled ----------------
__global__ void k_conv_items(const float* __restrict__ item_emb, const int* __restrict__ deg,
                             const unsigned char* __restrict__ w1, const unsigned char* __restrict__ w2,
                             const unsigned char* __restrict__ w3, ushort* __restrict__ item_bf) {
    int f = blockIdx.x * 256 + threadIdx.x;    // one 4-dim group
    if (f >= N_ITEMS_PAD * (D / 4)) return;
    int row = f >> 4, c4 = f & 15;
    ushort4 o;
    if (row < N_ITEMS) {
        int node = N_USERS + row;
        int dg = deg[node]; if (dg < 1) dg = 1;
        float s = sqrtf((float)dg) * (1.f / 256.f);    // sqrt(deg)/(64 scale * 4 avg)
        float4 e4 = ((const float4*)(item_emb + (size_t)(row + 1) * D))[c4];
        size_t n4 = (size_t)node * 16 + c4;
        uchar4 a = ((const uchar4*)w1)[n4];
        uchar4 b = ((const uchar4*)w2)[n4];
        uchar4 c = ((const uchar4*)w3)[n4];
        o.x = f2bf(LOG2E * (0.25f * e4.x + s * (fp82f(a.x) + fp82f(b.x) + fp82f(c.x))));
        o.y = f2bf(LOG2E * (0.25f * e4.y + s * (fp82f(a.y) + fp82f(b.y) + fp82f(c.y))));
        o.z = f2bf(LOG2E * (0.25f * e4.z + s * (fp82f(a.z) + fp82f(b.z) + fp82f(c.z))));
        o.w = f2bf(LOG2E * (0.25f * e4.w + s * (fp82f(a.w) + fp82f(b.w) + fp82f(c.w))));
    } else {
        o.x = o.y = o.z = o.w = 0;   // pad rows -> score 0 -> exp2 = 1 (subtract 96 in k_loss)
    }
    int tile = row >> 5, rr = row & 31;
    int q = c4 >> 2, half = (c4 >> 1) & 1, e0 = (c4 & 1) * 4;
    size_t idx = (size_t)tile * 2048 + q * 512 + (rr + 32 * half) * 8 + e0;
    *(ushort4*)(item_bf + idx) = o;
}

// ---------------- pred (bf16 copy) + label score ----------------
__global__ __launch_bounds__(256) void k_pred(const int* __restrict__ user_seqs, const int* __restrict__ his,
                                              const int* __restrict__ next_items,
                                              const float* __restrict__ user_emb, const float* __restrict__ item_emb,
                                              const int* __restrict__ deg,
                                              const unsigned char* __restrict__ w1, const unsigned char* __restrict__ w2,
                                              const unsigned char* __restrict__ w3,
                                              ushort* __restrict__ pred_bf, float* __restrict__ slabel) {
    int b = blockIdx.x * 4 + (threadIdx.x >> 6);
    int lane = threadIdx.x & 63;
    int u = user_seqs[b];
    float hsum = 0.f; int cnt = 0;
    for (int j = 0; j < HIST; ++j) {
        int it = his[b * HIST + j];
        cnt += (it != 0);
        hsum += item_emb[(size_t)it * D + lane];   // item_emb[0] is all-zero (pad)
    }
    int du = deg[u]; if (du < 1) du = 1;
    float su = sqrtf((float)du) * (1.f / 256.f);
    size_t ur = (size_t)u * D + lane;
    float ulat = 0.25f * user_emb[ur] + su * (fp82f(w1[ur]) + fp82f(w2[ur]) + fp82f(w3[ur]));
    float pv = ulat + hsum / (float)cnt;
    pred_bf[(size_t)b * D + lane] = f2bf(pv);
    int lab = next_items[b] - 1;
    int node = N_USERS + lab;
    int di = deg[node]; if (di < 1) di = 1;
    float si = sqrtf((float)di) * (1.f / 256.f);
    size_t nr = (size_t)node * D + lane;
    float ilat = 0.25f * item_emb[(size_t)(lab + 1) * D + lane]
               + si * (fp82f(w1[nr]) + fp82f(w2[nr]) + fp82f(w3[nr]));
    float tv = pv * ilat;
#pragma unroll
    for (int off = 32; off > 0; off >>= 1) tv += __shfl_down(tv, off);
    if (lane == 0) slabel[b] = tv;
}

// ---------------- MFMA scores + max-free sumexp (batch-stationary, frag-tiled items) ----------------
#define MFMA __builtin_amdgcn_mfma_f32_32x32x16_bf16
__global__ __launch_bounds__(256) void k_scores(const ushort* __restrict__ item_bf,
                                                const ushort* __restrict__ pred_bf,
                                                float* __restrict__ sumexp) {
    int t = threadIdx.x, wv = t >> 6, lane = t & 63;
    int l31 = lane & 31;
    int khalf = (lane >> 5) * 8;   // which 8-elem k-half this lane holds

    int brow = blockIdx.y * 128 + wv * 32 + l31;        // this lane's batch column
    const ushort* pb = pred_bf + (size_t)brow * D + khalf;
    short8 b0 = *(const short8*)(pb);
    short8 b1 = *(const short8*)(pb + 16);
    short8 b2 = *(const short8*)(pb + 32);
    short8 b3 = *(const short8*)(pb + 48);

    const ushort* ib = item_bf + (size_t)blockIdx.x * TPS * 2048 + lane * 8;
    float acc = 0.f;

    short8 x0 = *(const short8*)(ib);
    short8 x1 = *(const short8*)(ib + 512);
    short8 x2 = *(const short8*)(ib + 1024);
    short8 x3 = *(const short8*)(ib + 1536);
    short8 x4 = *(const short8*)(ib + 2048);
    short8 x5 = *(const short8*)(ib + 2560);
    short8 x6 = *(const short8*)(ib + 3072);
    short8 x7 = *(const short8*)(ib + 3584);

    for (int tt = 0; tt < TPS; tt += 2) {
        // prefetch next pair (last iteration reads 8KB past this split's tiles —
        // lands in the next split / pred_bf region, valid memory, never used)
        const ushort* in = ib + (size_t)(tt + 2) * 2048;
        short8 y0 = *(const short8*)(in);
        short8 y1 = *(const short8*)(in + 512);
        short8 y2 = *(const short8*)(in + 1024);
        short8 y3 = *(const short8*)(in + 1536);
        short8 y4 = *(const short8*)(in + 2048);
        short8 y5 = *(const short8*)(in + 2560);
        short8 y6 = *(const short8*)(in + 3072);
        short8 y7 = *(const short8*)(in + 3584);
        float16 c0 = {0.f};
        float16 c1 = {0.f};
        c0 = MFMA(x0, b0, c0, 0, 0, 0);
        c1 = MFMA(x4, b0, c1, 0, 0, 0);
        c0 = MFMA(x1, b1, c0, 0, 0, 0);
        c1 = MFMA(x5, b1, c1, 0, 0, 0);
        c0 = MFMA(x2, b2, c0, 0, 0, 0);
        c1 = MFMA(x6, b2, c1, 0, 0, 0);
        c0 = MFMA(x3, b3, c0, 0, 0, 0);
        c1 = MFMA(x7, b3, c1, 0, 0, 0);
        float s0 = 0.f, s1 = 0.f, s2 = 0.f, s3 = 0.f;
#pragma unroll
        for (int r = 0; r < 16; r += 4) {
            s0 += exp2fast(c0[r]);
            s1 += exp2fast(c0[r + 1]);
            s2 += exp2fast(c0[r + 2]);
            s3 += exp2fast(c0[r + 3]);
        }
#pragma unroll
        for (int r = 0; r < 16; r += 4) {
            s0 += exp2fast(c1[r]);
            s1 += exp2fast(c1[r + 1]);
            s2 += exp2fast(c1[r + 2]);
            s3 += exp2fast(c1[r + 3]);
        }
        acc += (s0 + s1) + (s2 + s3);
        x0 = y0; x1 = y1; x2 = y2; x3 = y3;
        x4 = y4; x5 = y5; x6 = y6; x7 = y7;
    }
    // lane L and L+32 hold the two item-row halves of the same batch col
    acc += __shfl_down(acc, 32);
    if (lane < 32) unsafeAtomicAdd(&sumexp[brow], acc);
}

// ---------------- final loss reduce ----------------
__global__ __launch_bounds__(256) void k_loss(const float* __restrict__ sumexp, const float* __restrict__ slabel,
                                              float* __restrict__ out) {
    __shared__ float ws[4];
    int t = threadIdx.x;
    float v = 0.f;
    for (int i = t; i < BATCH; i += 256)
        v += __logf(sumexp[i] - 96.0f) - slabel[i];   // -96: padded items contribute exp2(0)=1 each
#pragma unroll
    for (int off = 32; off > 0; off >>= 1) v += __shfl_down(v, off);
    if ((t & 63) == 0) ws[t >> 6] = v;
    __syncthreads();
    if (t == 0) out[0] = (ws[0] + ws[1] + ws[2] + ws[3]) * (1.f / (float)BATCH);
}

extern "C" void kernel_launch(void* const* d_in, const int* in_sizes, int n_in,
                              void* d_out, int out_size, void* d_ws, size_t ws_size,
                              hipStream_t stream) {
    const int*   user_seqs = (const int*)d_in[0];
    const int*   his       = (const int*)d_in[1];
    const int*   next_itm  = (const int*)d_in[2];
    const int*   adj_row   = (const int*)d_in[3];
    const int*   adj_col   = (const int*)d_in[4];
    const float* user_emb  = (const float*)d_in[6];
    const float* item_emb  = (const float*)d_in[7];
    float* out = (float*)d_out;
    int nedges = in_sizes[3];   // 12,800,000

    // Workspace layout (~183 MB). gcursor padded to 512 ints so every downstream
    // buffer stays 256B-aligned.
    unsigned char* w0 = (unsigned char*)d_ws;              // 12.8 MB each
    unsigned char* w1 = w0 + (size_t)N_NODES * D;
    unsigned char* w2 = w1 + (size_t)N_NODES * D;
    unsigned char* w3 = w2 + (size_t)N_NODES * D;
    float*  slabel = (float*)(w3 + (size_t)N_NODES * D);   // 2,048
    float*  sumexp = slabel + BATCH;                       // 2,048   (zeroed)
    int*    gcursor= (int*)(sumexp + BATCH);               // 512 (zeroed; 196 used)
    int*    rowptr = gcursor + 512;                        // 200,000
    int*    deg    = rowptr + N_NODES;                     // 200,000
    int*    staged = deg + N_NODES;                        // 196*73728 ints (57.8 MB)
    int*    ecols  = staged + (size_t)N_BUCKETS_RAW * BCAP; // 196*73728 ints (57.8 MB)
    ushort* item_bf = (ushort*)(ecols + (size_t)N_BUCKETS_RAW * BCAP);  // 100096*64 ushort, 256B-aligned
    ushort* pred_bf = item_bf + (size_t)N_ITEMS_PAD * D;   // 131072 ushort

    // zero sumexp + gcursor in one shot (contiguous)
    hipError_t _e = hipMemsetAsync(sumexp, 0, (size_t)(BATCH + 512) * sizeof(int), stream);
    (void)_e;

    int nchunks = (nedges + CHUNK - 1) / CHUNK;
    k_binA<<<nchunks, 256, 0, stream>>>(adj_row, adj_col, gcursor, staged, nedges);
    k_binB<<<N_BUCKETS_RAW, 1024, 0, stream>>>(gcursor, staged, ecols, rowptr, deg,
                                               user_emb, item_emb, w0);

    k_prop<<<N_NODES / 32, 256, 0, stream>>>(rowptr, deg, ecols, w0, w1);
    k_prop<<<N_NODES / 32, 256, 0, stream>>>(rowptr, deg, ecols, w1, w2);
    k_prop<<<N_NODES / 32, 256, 0, stream>>>(rowptr, deg, ecols, w2, w3);

    k_conv_items<<<(N_ITEMS_PAD * (D / 4) + 255) / 256, 256, 0, stream>>>(item_emb, deg, w1, w2, w3, item_bf);
    k_pred<<<BATCH / 4, 256, 0, stream>>>(user_seqs, his, next_itm, user_emb, item_emb, deg,
                                          w1, w2, w3, pred_bf, slabel);

    dim3 gs(ISPLITS, BATCH / 128);
    k_scores<<<gs, 256, 0, stream>>>(item_bf, pred_bf, sumexp);

    k_loss<<<1, 256, 0, stream>>>(sumexp, slabel, out);
}